// Round 2
// baseline (4238.581 us; speedup 1.0000x reference)
//
#include <hip/hip_runtime.h>
#include <math.h>

#define HW_  16384
#define Q_   200
#define C_   1024
#define L_   16584   // Q_ + HW_
#define NH_  16
#define HD_  64

// ---------------------------------------------------------------------------
// sigmoid(masks) -> msig [Q][HW]; w[q] = sum_l msig[q][l]
__global__ __launch_bounds__(256) void k_sigmoid_w(const float* __restrict__ masks,
                                                   float* __restrict__ msig,
                                                   float* __restrict__ w) {
  int q = blockIdx.x;
  int tid = threadIdx.x;
  const float* mrow = masks + (size_t)q * HW_;
  float* orow = msig + (size_t)q * HW_;
  float s = 0.f;
  for (int i = tid; i < HW_; i += 256) {
    float v = mrow[i];
    float sg = 1.f / (1.f + expf(-v));
    orow[i] = sg;
    s += sg;
  }
  __shared__ float red[256];
  red[tid] = s;
  __syncthreads();
  for (int off = 128; off > 0; off >>= 1) {
    if (tid < off) red[tid] += red[tid + off];
    __syncthreads();
  }
  if (tid == 0) w[q] = red[0];
}

// ---------------------------------------------------------------------------
// seq[Q_ + l][c] = x[c][l]   (pixel-token part of seq)
__global__ __launch_bounds__(256) void k_transpose(const float* __restrict__ x,
                                                   float* __restrict__ seq) {
  __shared__ float t[32][33];
  int l0 = blockIdx.x * 32;
  int c0 = blockIdx.y * 32;
  int tx = threadIdx.x, ty = threadIdx.y;  // (32, 8)
  #pragma unroll
  for (int i = 0; i < 32; i += 8)
    t[ty + i][tx] = x[(size_t)(c0 + ty + i) * HW_ + l0 + tx];
  __syncthreads();
  #pragma unroll
  for (int i = 0; i < 32; i += 8)
    seq[(size_t)(Q_ + l0 + ty + i) * C_ + c0 + tx] = t[tx][ty + i];
}

// ---------------------------------------------------------------------------
// C[m][n] = (sum_k A[m][k] * B[n][k] + bias[n]) * (wdiv ? 1/(wdiv[m]+1e-3) : 1)
// A: [M][K] row-major, B: [N][K] row-major (i.e. computes A @ B^T). N % 64 == 0.
#define BM 64
#define BN 64
#define BK 16
#define LDT 68   // padded leading dim, keeps float4 alignment (68 % 4 == 0)

__global__ __launch_bounds__(256) void k_gemm_abt(const float* __restrict__ A,
                                                  const float* __restrict__ B,
                                                  const float* __restrict__ bias,
                                                  const float* __restrict__ wdiv,
                                                  float* __restrict__ Cm,
                                                  int M, int N, int K) {
  __shared__ float As[BK][LDT];
  __shared__ float Bs[BK][LDT];
  int bm = blockIdx.y * BM, bn = blockIdx.x * BN;
  int tid = threadIdx.x;
  int lm = tid >> 2;          // 0..63  tile row being loaded
  int lk = (tid & 3) << 2;    // 0,4,8,12
  int r0 = (tid >> 4) << 2;   // output micro-tile rows
  int c0 = (tid & 15) << 2;   // output micro-tile cols
  float acc[4][4] = {};
  const float* Aload = A + (size_t)(bm + lm) * K + lk;
  const float* Bload = B + (size_t)(bn + lm) * K + lk;
  bool aok = (bm + lm) < M;
  for (int k0 = 0; k0 < K; k0 += BK) {
    float4 av = make_float4(0.f, 0.f, 0.f, 0.f);
    if (aok) av = *(const float4*)(Aload + k0);
    float4 bv = *(const float4*)(Bload + k0);
    __syncthreads();
    As[lk + 0][lm] = av.x; As[lk + 1][lm] = av.y;
    As[lk + 2][lm] = av.z; As[lk + 3][lm] = av.w;
    Bs[lk + 0][lm] = bv.x; Bs[lk + 1][lm] = bv.y;
    Bs[lk + 2][lm] = bv.z; Bs[lk + 3][lm] = bv.w;
    __syncthreads();
    #pragma unroll
    for (int kk = 0; kk < BK; kk++) {
      float4 a4 = *(const float4*)&As[kk][r0];
      float4 b4 = *(const float4*)&Bs[kk][c0];
      float a[4] = {a4.x, a4.y, a4.z, a4.w};
      float b[4] = {b4.x, b4.y, b4.z, b4.w};
      #pragma unroll
      for (int i = 0; i < 4; i++)
        #pragma unroll
        for (int j = 0; j < 4; j++)
          acc[i][j] = fmaf(a[i], b[j], acc[i][j]);
    }
  }
  #pragma unroll
  for (int i = 0; i < 4; i++) {
    int m = bm + r0 + i;
    if (m >= M) continue;
    float rs = 1.f;
    if (wdiv) rs = 1.f / (wdiv[m] + 0.001f);
    #pragma unroll
    for (int j = 0; j < 4; j++) {
      int n = bn + c0 + j;
      float v = acc[i][j];
      if (bias) v += bias[n];
      Cm[(size_t)m * N + n] = v * rs;
    }
  }
}

// ---------------------------------------------------------------------------
// Flash attention with (q,l) mask. Block = (head h, tile of 8 queries).
// Threads: 256 = 8 rows x 32 l-lanes. Each thread owns 2 head-dims of acc.
__global__ __launch_bounds__(256) void k_attn(const float* __restrict__ qb,
                                              const float* __restrict__ kb,
                                              const float* __restrict__ vb,
                                              const float* __restrict__ msig,
                                              float* __restrict__ ctx) {
  int h = blockIdx.x;
  int q0 = blockIdx.y * 8;
  int tid = threadIdx.x;
  int row = tid >> 5, li = tid & 31;
  int qi = q0 + row;
  __shared__ float qs[8][64];
  __shared__ float ks[32][65];
  __shared__ float vs[32][65];
  __shared__ float ps[8][32];
  for (int i = tid; i < 8 * 64; i += 256) {
    int r = i >> 6, d = i & 63;
    qs[r][d] = qb[(size_t)(q0 + r) * C_ + h * HD_ + d] * 0.125f;  // hd^-0.5
  }
  float m_run = -INFINITY, l_run = 0.f, acc0 = 0.f, acc1 = 0.f;
  const int d0 = li * 2, d1 = li * 2 + 1;
  __syncthreads();
  for (int l0 = 0; l0 < L_; l0 += 32) {
    for (int i = tid; i < 32 * 64; i += 256) {
      int r = i >> 6, d = i & 63;
      int l = l0 + r;
      float kk = 0.f, vv = 0.f;
      if (l < L_) {
        kk = kb[(size_t)l * C_ + h * HD_ + d];
        vv = vb[(size_t)l * C_ + h * HD_ + d];
      }
      ks[r][d] = kk;
      vs[r][d] = vv;
    }
    __syncthreads();
    int l = l0 + li;
    bool allowed;
    if (l >= L_)      allowed = false;
    else if (l < Q_)  allowed = (l == qi);
    else              allowed = msig[(size_t)qi * HW_ + (l - Q_)] > 0.9f;
    float s = -INFINITY;
    if (allowed) {
      float a = 0.f;
      #pragma unroll
      for (int d = 0; d < 64; d++) a = fmaf(qs[row][d], ks[li][d], a);
      s = a;
    }
    float mt = s;
    #pragma unroll
    for (int off = 16; off; off >>= 1) mt = fmaxf(mt, __shfl_xor(mt, off));
    float p = 0.f;
    float m_new = fmaxf(m_run, mt);
    float scale = 1.f;
    if (m_new != -INFINITY) {
      scale = expf(m_run - m_new);          // m_run == -inf -> 0
      if (allowed) p = expf(s - m_new);
    }
    float psum = p;
    #pragma unroll
    for (int off = 16; off; off >>= 1) psum += __shfl_xor(psum, off);
    m_run = m_new;
    l_run = l_run * scale + psum;
    acc0 *= scale; acc1 *= scale;
    ps[row][li] = p;
    __syncthreads();
    if (psum > 0.f) {
      #pragma unroll
      for (int ll = 0; ll < 32; ll++) {
        float pv = ps[row][ll];
        acc0 = fmaf(pv, vs[ll][d0], acc0);
        acc1 = fmaf(pv, vs[ll][d1], acc1);
      }
    }
    __syncthreads();
  }
  float inv = 1.f / l_run;
  ctx[(size_t)qi * C_ + h * HD_ + d0] = acc0 * inv;
  ctx[(size_t)qi * C_ + h * HD_ + d1] = acc1 * inv;
}

// ---------------------------------------------------------------------------
extern "C" void kernel_launch(void* const* d_in, const int* in_sizes, int n_in,
                              void* d_out, int out_size, void* d_ws, size_t ws_size,
                              hipStream_t stream) {
  const float* x     = (const float*)d_in[0];
  const float* masks = (const float*)d_in[1];
  const float* Wq    = (const float*)d_in[2];
  const float* bq    = (const float*)d_in[3];
  const float* Wk    = (const float*)d_in[4];
  const float* bk    = (const float*)d_in[5];
  const float* Wv    = (const float*)d_in[6];
  const float* bv    = (const float*)d_in[7];
  const float* Wc    = (const float*)d_in[8];
  const float* bc    = (const float*)d_in[9];
  float* out = (float*)d_out;

  float* ws   = (float*)d_ws;
  float* msig = ws;                              // Q*HW
  float* w    = msig + (size_t)Q_ * HW_;         // 256 (padded)
  float* seq  = w + 256;                         // L*C  (rows 0..Q-1 = mean)
  float* kbuf = seq + (size_t)L_ * C_;           // L*C
  float* vbuf = kbuf + (size_t)L_ * C_;          // L*C
  float* ctx  = vbuf + (size_t)L_ * C_;          // Q*C
  float* qbuf = ctx + (size_t)Q_ * C_;           // Q*C

  k_sigmoid_w<<<Q_, 256, 0, stream>>>(masks, msig, w);
  k_transpose<<<dim3(HW_ / 32, C_ / 32), dim3(32, 8), 0, stream>>>(x, seq);
  // mean (into seq rows 0..Q-1): A = msig [Q][HW], B = x [C][HW]
  k_gemm_abt<<<dim3(C_ / BN, (Q_ + BM - 1) / BM), 256, 0, stream>>>(
      msig, x, nullptr, w, seq, Q_, C_, HW_);
  // q projection: A = mean rows of seq
  k_gemm_abt<<<dim3(C_ / BN, (Q_ + BM - 1) / BM), 256, 0, stream>>>(
      seq, Wq, bq, nullptr, qbuf, Q_, C_, C_);
  // k, v projections over full seq
  k_gemm_abt<<<dim3(C_ / BN, (L_ + BM - 1) / BM), 256, 0, stream>>>(
      seq, Wk, bk, nullptr, kbuf, L_, C_, C_);
  k_gemm_abt<<<dim3(C_ / BN, (L_ + BM - 1) / BM), 256, 0, stream>>>(
      seq, Wv, bv, nullptr, vbuf, L_, C_, C_);
  // attention
  k_attn<<<dim3(NH_, Q_ / 8), 256, 0, stream>>>(qbuf, kbuf, vbuf, msig, ctx);
  // output projection
  k_gemm_abt<<<dim3(C_ / BN, (Q_ + BM - 1) / BM), 256, 0, stream>>>(
      ctx, Wc, bc, nullptr, out, Q_, C_, C_);
}

// Round 3
// 2182.136 us; speedup vs baseline: 1.9424x; 1.9424x over previous
//
#include <hip/hip_runtime.h>
#include <math.h>

#define HW_  16384
#define Q_   200
#define C_   1024
#define L_   16584   // Q_ + HW_
#define NH_  16
#define HD_  64
#define CAP  2048    // max allowed-list entries per query (observed ~228)

// ---------------------------------------------------------------------------
// sigmoid(masks) -> msig [Q][HW]; w[q] = sum_l msig[q][l]
__global__ __launch_bounds__(256) void k_sigmoid_w(const float* __restrict__ masks,
                                                   float* __restrict__ msig,
                                                   float* __restrict__ w) {
  int q = blockIdx.x;
  int tid = threadIdx.x;
  const float* mrow = masks + (size_t)q * HW_;
  float* orow = msig + (size_t)q * HW_;
  float s = 0.f;
  for (int i = tid; i < HW_; i += 256) {
    float v = mrow[i];
    float sg = 1.f / (1.f + expf(-v));
    orow[i] = sg;
    s += sg;
  }
  __shared__ float red[256];
  red[tid] = s;
  __syncthreads();
  for (int off = 128; off > 0; off >>= 1) {
    if (tid < off) red[tid] += red[tid + off];
    __syncthreads();
  }
  if (tid == 0) w[q] = red[0];
}

// ---------------------------------------------------------------------------
// Deterministic per-query compaction of allowed pixel indices.
// List layout: idx[q][0] = q (self pooled token, always allowed);
//              idx[q][1..] = Q_ + pixel for msig[q][pixel] > 0.9.
__global__ __launch_bounds__(256) void k_compact(const float* __restrict__ msig,
                                                 int* __restrict__ cnt,
                                                 int* __restrict__ idxg) {
  int q = blockIdx.x;
  int tid = threadIdx.x;
  const float* mrow = msig + (size_t)q * HW_;
  const int CHUNK = HW_ / 256;  // 64
  int base = tid * CHUNK;
  int my = 0;
  for (int j = 0; j < CHUNK; j++) my += (mrow[base + j] > 0.9f) ? 1 : 0;
  __shared__ int sc[256];
  sc[tid] = my;
  __syncthreads();
  // Hillis-Steele inclusive scan
  for (int off = 1; off < 256; off <<= 1) {
    int v = sc[tid];
    int add = (tid >= off) ? sc[tid - off] : 0;
    __syncthreads();
    sc[tid] = v + add;
    __syncthreads();
  }
  int excl = sc[tid] - my;
  int total = sc[255];
  int* orow = idxg + (size_t)q * CAP;
  int off = 1 + excl;  // slot 0 = self
  for (int j = 0; j < CHUNK; j++) {
    if (mrow[base + j] > 0.9f) {
      if (off < CAP) orow[off] = Q_ + base + j;
      off++;
    }
  }
  if (tid == 0) {
    orow[0] = q;
    int c = 1 + total;
    cnt[q] = c < CAP ? c : CAP;
  }
}

// ---------------------------------------------------------------------------
// seq[Q_ + l][c] = x[c][l]   (pixel-token part of seq)
__global__ __launch_bounds__(256) void k_transpose(const float* __restrict__ x,
                                                   float* __restrict__ seq) {
  __shared__ float t[32][33];
  int l0 = blockIdx.x * 32;
  int c0 = blockIdx.y * 32;
  int tx = threadIdx.x, ty = threadIdx.y;  // (32, 8)
  #pragma unroll
  for (int i = 0; i < 32; i += 8)
    t[ty + i][tx] = x[(size_t)(c0 + ty + i) * HW_ + l0 + tx];
  __syncthreads();
  #pragma unroll
  for (int i = 0; i < 32; i += 8)
    seq[(size_t)(Q_ + l0 + ty + i) * C_ + c0 + tx] = t[tx][ty + i];
}

// ---------------------------------------------------------------------------
// C[m][n] = (sum_k A[m][k] * B[n][k] + bias[n]) * (wdiv ? 1/(wdiv[m]+1e-3) : 1)
#define BM 64
#define BN 64
#define BK 16
#define LDT 68

__global__ __launch_bounds__(256) void k_gemm_abt(const float* __restrict__ A,
                                                  const float* __restrict__ B,
                                                  const float* __restrict__ bias,
                                                  const float* __restrict__ wdiv,
                                                  float* __restrict__ Cm,
                                                  int M, int N, int K) {
  __shared__ float As[BK][LDT];
  __shared__ float Bs[BK][LDT];
  int bm = blockIdx.y * BM, bn = blockIdx.x * BN;
  int tid = threadIdx.x;
  int lm = tid >> 2;
  int lk = (tid & 3) << 2;
  int r0 = (tid >> 4) << 2;
  int c0 = (tid & 15) << 2;
  float acc[4][4] = {};
  const float* Aload = A + (size_t)(bm + lm) * K + lk;
  const float* Bload = B + (size_t)(bn + lm) * K + lk;
  bool aok = (bm + lm) < M;
  for (int k0 = 0; k0 < K; k0 += BK) {
    float4 av = make_float4(0.f, 0.f, 0.f, 0.f);
    if (aok) av = *(const float4*)(Aload + k0);
    float4 bv = *(const float4*)(Bload + k0);
    __syncthreads();
    As[lk + 0][lm] = av.x; As[lk + 1][lm] = av.y;
    As[lk + 2][lm] = av.z; As[lk + 3][lm] = av.w;
    Bs[lk + 0][lm] = bv.x; Bs[lk + 1][lm] = bv.y;
    Bs[lk + 2][lm] = bv.z; Bs[lk + 3][lm] = bv.w;
    __syncthreads();
    #pragma unroll
    for (int kk = 0; kk < BK; kk++) {
      float4 a4 = *(const float4*)&As[kk][r0];
      float4 b4 = *(const float4*)&Bs[kk][c0];
      float a[4] = {a4.x, a4.y, a4.z, a4.w};
      float b[4] = {b4.x, b4.y, b4.z, b4.w};
      #pragma unroll
      for (int i = 0; i < 4; i++)
        #pragma unroll
        for (int j = 0; j < 4; j++)
          acc[i][j] = fmaf(a[i], b[j], acc[i][j]);
    }
  }
  #pragma unroll
  for (int i = 0; i < 4; i++) {
    int m = bm + r0 + i;
    if (m >= M) continue;
    float rs = 1.f;
    if (wdiv) rs = 1.f / (wdiv[m] + 0.001f);
    #pragma unroll
    for (int j = 0; j < 4; j++) {
      int n = bn + c0 + j;
      float v = acc[i][j];
      if (bias) v += bias[n];
      Cm[(size_t)m * N + n] = v * rs;
    }
  }
}

// ---------------------------------------------------------------------------
// Sparse gather attention. Block = (q, h). Scores only over allowed list.
__global__ __launch_bounds__(256) void k_sparse_attn(const float* __restrict__ qb,
                                                     const float* __restrict__ kb,
                                                     const float* __restrict__ vb,
                                                     const int* __restrict__ cnt_g,
                                                     const int* __restrict__ idxg,
                                                     float* __restrict__ ctx) {
  int q = blockIdx.x;
  int h = blockIdx.y;
  int tid = threadIdx.x;
  int lane = tid & 63, wid = tid >> 6;

  __shared__ float qs[64];
  __shared__ float scores[CAP];
  __shared__ int   ls[CAP];
  __shared__ float wred[4];
  __shared__ float accb[4][64];
  __shared__ float Sshared;

  int cnt = cnt_g[q];
  const int* myidx = idxg + (size_t)q * CAP;
  if (tid < 64) qs[tid] = qb[(size_t)q * C_ + h * HD_ + tid] * 0.125f;
  __syncthreads();

  // scores
  for (int i = tid; i < cnt; i += 256) {
    int l = myidx[i];
    ls[i] = l;
    const float* kr = kb + (size_t)l * C_ + h * HD_;
    float s = 0.f;
    #pragma unroll
    for (int d4 = 0; d4 < 16; d4++) {
      float4 kv = *(const float4*)(kr + d4 * 4);
      s = fmaf(qs[d4 * 4 + 0], kv.x, s);
      s = fmaf(qs[d4 * 4 + 1], kv.y, s);
      s = fmaf(qs[d4 * 4 + 2], kv.z, s);
      s = fmaf(qs[d4 * 4 + 3], kv.w, s);
    }
    scores[i] = s;
  }
  __syncthreads();

  // block max
  float lm = -INFINITY;
  for (int i = tid; i < cnt; i += 256) lm = fmaxf(lm, scores[i]);
  #pragma unroll
  for (int off = 32; off; off >>= 1) lm = fmaxf(lm, __shfl_xor(lm, off));
  if (lane == 0) wred[wid] = lm;
  __syncthreads();
  float m = fmaxf(fmaxf(wred[0], wred[1]), fmaxf(wred[2], wred[3]));

  // exp + sum
  float lsum = 0.f;
  for (int i = tid; i < cnt; i += 256) {
    float e = expf(scores[i] - m);
    scores[i] = e;
    lsum += e;
  }
  #pragma unroll
  for (int off = 32; off; off >>= 1) lsum += __shfl_xor(lsum, off);
  __syncthreads();   // all reads of wred (max) done before overwrite
  if (lane == 0) wred[wid] = lsum;
  __syncthreads();
  if (tid == 0) Sshared = wred[0] + wred[1] + wred[2] + wred[3];

  // PV: wave w takes i = w, w+4, ...; lane owns dim d = lane
  float acc = 0.f;
  for (int i = wid; i < cnt; i += 4) {
    float p = scores[i];
    const float* vr = vb + (size_t)ls[i] * C_ + h * HD_;
    acc = fmaf(p, vr[lane], acc);
  }
  accb[wid][lane] = acc;
  __syncthreads();
  if (tid < 64) {
    float tot = accb[0][tid] + accb[1][tid] + accb[2][tid] + accb[3][tid];
    ctx[(size_t)q * C_ + h * HD_ + tid] = tot / Sshared;
  }
}

// ---------------------------------------------------------------------------
extern "C" void kernel_launch(void* const* d_in, const int* in_sizes, int n_in,
                              void* d_out, int out_size, void* d_ws, size_t ws_size,
                              hipStream_t stream) {
  const float* x     = (const float*)d_in[0];
  const float* masks = (const float*)d_in[1];
  const float* Wq    = (const float*)d_in[2];
  const float* bq    = (const float*)d_in[3];
  const float* Wk    = (const float*)d_in[4];
  const float* bk    = (const float*)d_in[5];
  const float* Wv    = (const float*)d_in[6];
  const float* bv    = (const float*)d_in[7];
  const float* Wc    = (const float*)d_in[8];
  const float* bc    = (const float*)d_in[9];
  float* out = (float*)d_out;

  float* ws   = (float*)d_ws;
  float* msig = ws;                              // Q*HW
  float* w    = msig + (size_t)Q_ * HW_;         // 256 (padded)
  float* seq  = w + 256;                         // L*C (rows 0..Q-1 = mean)
  float* kbuf = seq + (size_t)L_ * C_;           // L*C
  float* vbuf = kbuf + (size_t)L_ * C_;          // L*C
  float* ctx  = vbuf + (size_t)L_ * C_;          // Q*C
  float* qbuf = ctx + (size_t)Q_ * C_;           // Q*C
  int*   cnt  = (int*)(qbuf + (size_t)Q_ * C_);  // 256
  int*   idxg = cnt + 256;                       // Q*CAP

  k_sigmoid_w<<<Q_, 256, 0, stream>>>(masks, msig, w);
  k_compact<<<Q_, 256, 0, stream>>>(msig, cnt, idxg);
  k_transpose<<<dim3(HW_ / 32, C_ / 32), dim3(32, 8), 0, stream>>>(x, seq);
  // mask-weighted mean (into seq rows 0..Q-1)
  k_gemm_abt<<<dim3(C_ / BN, (Q_ + BM - 1) / BM), 256, 0, stream>>>(
      msig, x, nullptr, w, seq, Q_, C_, HW_);
  // q projection
  k_gemm_abt<<<dim3(C_ / BN, (Q_ + BM - 1) / BM), 256, 0, stream>>>(
      seq, Wq, bq, nullptr, qbuf, Q_, C_, C_);
  // k, v projections
  k_gemm_abt<<<dim3(C_ / BN, (L_ + BM - 1) / BM), 256, 0, stream>>>(
      seq, Wk, bk, nullptr, kbuf, L_, C_, C_);
  k_gemm_abt<<<dim3(C_ / BN, (L_ + BM - 1) / BM), 256, 0, stream>>>(
      seq, Wv, bv, nullptr, vbuf, L_, C_, C_);
  // sparse attention
  k_sparse_attn<<<dim3(Q_, NH_), 256, 0, stream>>>(qbuf, kbuf, vbuf, cnt, idxg, ctx);
  // output projection
  k_gemm_abt<<<dim3(C_ / BN, (Q_ + BM - 1) / BM), 256, 0, stream>>>(
      ctx, Wc, bc, nullptr, out, Q_, C_, C_);
}

// Round 4
// 566.770 us; speedup vs baseline: 7.4785x; 3.8501x over previous
//
#include <hip/hip_runtime.h>
#include <math.h>

#define HW_  16384
#define Q_   200
#define C_   1024
#define L_   16584   // Q_ + HW_
#define NH_  16
#define HD_  64
#define CAP  2048
#define KSPLIT 8
#define KCH  (HW_ / KSPLIT)   // 2048

typedef __attribute__((ext_vector_type(8))) __bf16 bf16x8;
typedef __attribute__((ext_vector_type(4))) float f32x4;

__device__ inline unsigned short f2bf(float f) {
  unsigned int u = __float_as_uint(f);
  u += 0x7fff + ((u >> 16) & 1);   // round-to-nearest-even
  return (unsigned short)(u >> 16);
}

// ---------------------------------------------------------------------------
// sigmoid(masks) -> msig fp32 + msigbf bf16 (rows >= Q_ zeroed); w[q] = row sum
__global__ __launch_bounds__(256) void k_sigmoid_w(const float* __restrict__ masks,
                                                   float* __restrict__ msig,
                                                   unsigned short* __restrict__ msigbf,
                                                   float* __restrict__ w) {
  int q = blockIdx.x;
  int tid = threadIdx.x;
  unsigned short* obf = msigbf + (size_t)q * HW_;
  if (q >= Q_) {
    for (int i = tid; i < HW_; i += 256) obf[i] = 0;
    return;
  }
  const float* mrow = masks + (size_t)q * HW_;
  float* orow = msig + (size_t)q * HW_;
  float s = 0.f;
  for (int i = tid; i < HW_; i += 256) {
    float v = mrow[i];
    float sg = 1.f / (1.f + expf(-v));
    orow[i] = sg;
    obf[i] = f2bf(sg);
    s += sg;
  }
  __shared__ float red[256];
  red[tid] = s;
  __syncthreads();
  for (int off = 128; off > 0; off >>= 1) {
    if (tid < off) red[tid] += red[tid + off];
    __syncthreads();
  }
  if (tid == 0) w[q] = red[0];
}

// ---------------------------------------------------------------------------
// Deterministic per-query compaction of allowed pixel indices.
__global__ __launch_bounds__(256) void k_compact(const float* __restrict__ msig,
                                                 int* __restrict__ cnt,
                                                 int* __restrict__ idxg) {
  int q = blockIdx.x;
  int tid = threadIdx.x;
  const float* mrow = msig + (size_t)q * HW_;
  const int CHUNK = HW_ / 256;  // 64
  int base = tid * CHUNK;
  int my = 0;
  for (int j = 0; j < CHUNK; j++) my += (mrow[base + j] > 0.9f) ? 1 : 0;
  __shared__ int sc[256];
  sc[tid] = my;
  __syncthreads();
  for (int off = 1; off < 256; off <<= 1) {
    int v = sc[tid];
    int add = (tid >= off) ? sc[tid - off] : 0;
    __syncthreads();
    sc[tid] = v + add;
    __syncthreads();
  }
  int excl = sc[tid] - my;
  int total = sc[255];
  int* orow = idxg + (size_t)q * CAP;
  int off = 1 + excl;  // slot 0 = self
  for (int j = 0; j < CHUNK; j++) {
    if (mrow[base + j] > 0.9f) {
      if (off < CAP) orow[off] = Q_ + base + j;
      off++;
    }
  }
  if (tid == 0) {
    orow[0] = q;
    int c = 1 + total;
    cnt[q] = c < CAP ? c : CAP;
  }
}

// ---------------------------------------------------------------------------
// x [C][HW] fp32 -> xbf [C][HW] bf16 (same layout) + seqbf pixel rows (transposed)
__global__ __launch_bounds__(256) void k_xcast(const float* __restrict__ x,
                                               unsigned short* __restrict__ xbf,
                                               unsigned short* __restrict__ seqbf) {
  __shared__ float t[32][33];
  int l0 = blockIdx.x * 32, c0 = blockIdx.y * 32;
  int tx = threadIdx.x, ty = threadIdx.y;  // (32,8)
  #pragma unroll
  for (int i = 0; i < 32; i += 8) {
    float v = x[(size_t)(c0 + ty + i) * HW_ + l0 + tx];
    t[ty + i][tx] = v;
    xbf[(size_t)(c0 + ty + i) * HW_ + l0 + tx] = f2bf(v);
  }
  __syncthreads();
  #pragma unroll
  for (int i = 0; i < 32; i += 8)
    seqbf[(size_t)(Q_ + l0 + ty + i) * C_ + c0 + tx] = f2bf(t[tx][ty + i]);
}

// ---------------------------------------------------------------------------
__global__ __launch_bounds__(256) void k_cast(const float* __restrict__ in,
                                              unsigned short* __restrict__ out, int n) {
  int stride = gridDim.x * 256;
  for (int i = blockIdx.x * 256 + threadIdx.x; i < n; i += stride)
    out[i] = f2bf(in[i]);
}

// ---------------------------------------------------------------------------
// bf16 MFMA GEMM: C[m][n] = sum_k A[m][k]*B[n][k] + bias[n]; A:[M][K], B:[1024][K]
// 128x128 tile, BK=32, 4 waves (2x2), each wave 64x64 via 4x4 16x16x32 MFMA.
#define GBM 128
#define GBN 128
#define GBK 32

__global__ __launch_bounds__(256) void k_gemm_bf(const unsigned short* __restrict__ A,
                                                 const unsigned short* __restrict__ B,
                                                 const float* __restrict__ bias,
                                                 float* __restrict__ Cm,
                                                 int M, int K) {
  __shared__ __attribute__((aligned(16))) unsigned short As[GBM][GBK];
  __shared__ __attribute__((aligned(16))) unsigned short Bs[GBN][GBK];
  int bm = blockIdx.y * GBM, bn = blockIdx.x * GBN;
  int tid = threadIdx.x;
  int wid = tid >> 6, lane = tid & 63;
  int wr = wid >> 1, wc = wid & 1;
  int fq = lane >> 4, fr = lane & 15;
  int srow = lane >> 2;            // staging row within 16-row chunk
  int scol = (lane & 3) * 8;       // staging k-offset (elements)
  f32x4 acc[4][4] = {};
  for (int k0 = 0; k0 < K; k0 += GBK) {
    __syncthreads();
    #pragma unroll
    for (int i = 0; i < 2; i++) {
      int r = wid * 32 + i * 16 + srow;
      int gA = bm + r; if (gA > M - 1) gA = M - 1;
      __builtin_amdgcn_global_load_lds(
          (const __attribute__((address_space(1))) void*)(A + (size_t)gA * K + k0 + scol),
          (__attribute__((address_space(3))) void*)((char*)&As[0][0] + (wid * 2 + i) * 1024),
          16, 0, 0);
      int gB = bn + r;
      __builtin_amdgcn_global_load_lds(
          (const __attribute__((address_space(1))) void*)(B + (size_t)gB * K + k0 + scol),
          (__attribute__((address_space(3))) void*)((char*)&Bs[0][0] + (wid * 2 + i) * 1024),
          16, 0, 0);
    }
    __syncthreads();
    bf16x8 af[4], bfr[4];
    #pragma unroll
    for (int mi = 0; mi < 4; mi++)
      af[mi] = *(const bf16x8*)&As[wr * 64 + mi * 16 + fr][fq * 8];
    #pragma unroll
    for (int ni = 0; ni < 4; ni++)
      bfr[ni] = *(const bf16x8*)&Bs[wc * 64 + ni * 16 + fr][fq * 8];
    #pragma unroll
    for (int mi = 0; mi < 4; mi++)
      #pragma unroll
      for (int ni = 0; ni < 4; ni++)
        acc[mi][ni] = __builtin_amdgcn_mfma_f32_16x16x32_bf16(af[mi], bfr[ni], acc[mi][ni], 0, 0, 0);
  }
  #pragma unroll
  for (int ni = 0; ni < 4; ni++) {
    int n = bn + wc * 64 + ni * 16 + fr;
    float bv = bias ? bias[n] : 0.f;
    #pragma unroll
    for (int mi = 0; mi < 4; mi++)
      #pragma unroll
      for (int j = 0; j < 4; j++) {
        int m = bm + wr * 64 + mi * 16 + fq * 4 + j;
        if (m < M) Cm[(size_t)m * C_ + n] = acc[mi][ni][j] + bv;
      }
  }
}

// ---------------------------------------------------------------------------
// Split-K mean GEMM: A = msigbf [256][HW_], B = xbf [1024][HW_]; z = K-chunk.
// partial[kc][m][n] fp32.
__global__ __launch_bounds__(256) void k_gemm_meank(const unsigned short* __restrict__ A,
                                                    const unsigned short* __restrict__ B,
                                                    float* __restrict__ partial) {
  __shared__ __attribute__((aligned(16))) unsigned short As[GBM][GBK];
  __shared__ __attribute__((aligned(16))) unsigned short Bs[GBN][GBK];
  int bm = blockIdx.y * GBM, bn = blockIdx.x * GBN;
  int kc = blockIdx.z;
  int tid = threadIdx.x;
  int wid = tid >> 6, lane = tid & 63;
  int wr = wid >> 1, wc = wid & 1;
  int fq = lane >> 4, fr = lane & 15;
  int srow = lane >> 2;
  int scol = (lane & 3) * 8;
  f32x4 acc[4][4] = {};
  int kbeg = kc * KCH, kend = kbeg + KCH;
  for (int k0 = kbeg; k0 < kend; k0 += GBK) {
    __syncthreads();
    #pragma unroll
    for (int i = 0; i < 2; i++) {
      int r = wid * 32 + i * 16 + srow;
      __builtin_amdgcn_global_load_lds(
          (const __attribute__((address_space(1))) void*)(A + (size_t)(bm + r) * HW_ + k0 + scol),
          (__attribute__((address_space(3))) void*)((char*)&As[0][0] + (wid * 2 + i) * 1024),
          16, 0, 0);
      __builtin_amdgcn_global_load_lds(
          (const __attribute__((address_space(1))) void*)(B + (size_t)(bn + r) * HW_ + k0 + scol),
          (__attribute__((address_space(3))) void*)((char*)&Bs[0][0] + (wid * 2 + i) * 1024),
          16, 0, 0);
    }
    __syncthreads();
    bf16x8 af[4], bfr[4];
    #pragma unroll
    for (int mi = 0; mi < 4; mi++)
      af[mi] = *(const bf16x8*)&As[wr * 64 + mi * 16 + fr][fq * 8];
    #pragma unroll
    for (int ni = 0; ni < 4; ni++)
      bfr[ni] = *(const bf16x8*)&Bs[wc * 64 + ni * 16 + fr][fq * 8];
    #pragma unroll
    for (int mi = 0; mi < 4; mi++)
      #pragma unroll
      for (int ni = 0; ni < 4; ni++)
        acc[mi][ni] = __builtin_amdgcn_mfma_f32_16x16x32_bf16(af[mi], bfr[ni], acc[mi][ni], 0, 0, 0);
  }
  #pragma unroll
  for (int ni = 0; ni < 4; ni++) {
    int n = bn + wc * 64 + ni * 16 + fr;
    #pragma unroll
    for (int mi = 0; mi < 4; mi++)
      #pragma unroll
      for (int j = 0; j < 4; j++) {
        int m = bm + wr * 64 + mi * 16 + fq * 4 + j;
        partial[((size_t)kc * 256 + m) * C_ + n] = acc[mi][ni][j];
      }
  }
}

// ---------------------------------------------------------------------------
__global__ __launch_bounds__(256) void k_mean_reduce(const float* __restrict__ partial,
                                                     const float* __restrict__ w,
                                                     float* __restrict__ meanf,
                                                     unsigned short* __restrict__ seqbf) {
  int m = blockIdx.x;  // 0..Q_-1
  float rs = 1.f / (w[m] + 0.001f);
  for (int n = threadIdx.x; n < C_; n += 256) {
    float s = 0.f;
    #pragma unroll
    for (int kc = 0; kc < KSPLIT; kc++)
      s += partial[((size_t)kc * 256 + m) * C_ + n];
    s *= rs;
    meanf[(size_t)m * C_ + n] = s;
    seqbf[(size_t)m * C_ + n] = f2bf(s);
  }
}

// ---------------------------------------------------------------------------
// fp32 GEMM (A @ B^T + bias) for small M (Q / out projections).
#define BM 64
#define BN 64
#define BK 16
#define LDT 68

__global__ __launch_bounds__(256) void k_gemm_abt(const float* __restrict__ A,
                                                  const float* __restrict__ B,
                                                  const float* __restrict__ bias,
                                                  float* __restrict__ Cm,
                                                  int M, int N, int K) {
  __shared__ float As[BK][LDT];
  __shared__ float Bs[BK][LDT];
  int bm = blockIdx.y * BM, bn = blockIdx.x * BN;
  int tid = threadIdx.x;
  int lm = tid >> 2;
  int lk = (tid & 3) << 2;
  int r0 = (tid >> 4) << 2;
  int c0 = (tid & 15) << 2;
  float acc[4][4] = {};
  const float* Aload = A + (size_t)(bm + lm) * K + lk;
  const float* Bload = B + (size_t)(bn + lm) * K + lk;
  bool aok = (bm + lm) < M;
  for (int k0 = 0; k0 < K; k0 += BK) {
    float4 av = make_float4(0.f, 0.f, 0.f, 0.f);
    if (aok) av = *(const float4*)(Aload + k0);
    float4 bv = *(const float4*)(Bload + k0);
    __syncthreads();
    As[lk + 0][lm] = av.x; As[lk + 1][lm] = av.y;
    As[lk + 2][lm] = av.z; As[lk + 3][lm] = av.w;
    Bs[lk + 0][lm] = bv.x; Bs[lk + 1][lm] = bv.y;
    Bs[lk + 2][lm] = bv.z; Bs[lk + 3][lm] = bv.w;
    __syncthreads();
    #pragma unroll
    for (int kk = 0; kk < BK; kk++) {
      float4 a4 = *(const float4*)&As[kk][r0];
      float4 b4 = *(const float4*)&Bs[kk][c0];
      float a[4] = {a4.x, a4.y, a4.z, a4.w};
      float b[4] = {b4.x, b4.y, b4.z, b4.w};
      #pragma unroll
      for (int i = 0; i < 4; i++)
        #pragma unroll
        for (int j = 0; j < 4; j++)
          acc[i][j] = fmaf(a[i], b[j], acc[i][j]);
    }
  }
  #pragma unroll
  for (int i = 0; i < 4; i++) {
    int m = bm + r0 + i;
    if (m >= M) continue;
    #pragma unroll
    for (int j = 0; j < 4; j++) {
      int n = bn + c0 + j;
      float v = acc[i][j];
      if (bias) v += bias[n];
      Cm[(size_t)m * N + n] = v;
    }
  }
}

// ---------------------------------------------------------------------------
// Sparse gather attention. Block = (q, h).
__global__ __launch_bounds__(256) void k_sparse_attn(const float* __restrict__ qb,
                                                     const float* __restrict__ kb,
                                                     const float* __restrict__ vb,
                                                     const int* __restrict__ cnt_g,
                                                     const int* __restrict__ idxg,
                                                     float* __restrict__ ctx) {
  int q = blockIdx.x;
  int h = blockIdx.y;
  int tid = threadIdx.x;
  int lane = tid & 63, wid = tid >> 6;

  __shared__ float qs[64];
  __shared__ float scores[CAP];
  __shared__ int   ls[CAP];
  __shared__ float wred[4];
  __shared__ float accb[4][64];
  __shared__ float Sshared;

  int cnt = cnt_g[q];
  const int* myidx = idxg + (size_t)q * CAP;
  if (tid < 64) qs[tid] = qb[(size_t)q * C_ + h * HD_ + tid] * 0.125f;
  __syncthreads();

  for (int i = tid; i < cnt; i += 256) {
    int l = myidx[i];
    ls[i] = l;
    const float* kr = kb + (size_t)l * C_ + h * HD_;
    float s = 0.f;
    #pragma unroll
    for (int d4 = 0; d4 < 16; d4++) {
      float4 kv = *(const float4*)(kr + d4 * 4);
      s = fmaf(qs[d4 * 4 + 0], kv.x, s);
      s = fmaf(qs[d4 * 4 + 1], kv.y, s);
      s = fmaf(qs[d4 * 4 + 2], kv.z, s);
      s = fmaf(qs[d4 * 4 + 3], kv.w, s);
    }
    scores[i] = s;
  }
  __syncthreads();

  float lm = -INFINITY;
  for (int i = tid; i < cnt; i += 256) lm = fmaxf(lm, scores[i]);
  #pragma unroll
  for (int off = 32; off; off >>= 1) lm = fmaxf(lm, __shfl_xor(lm, off));
  if (lane == 0) wred[wid] = lm;
  __syncthreads();
  float m = fmaxf(fmaxf(wred[0], wred[1]), fmaxf(wred[2], wred[3]));

  float lsum = 0.f;
  for (int i = tid; i < cnt; i += 256) {
    float e = expf(scores[i] - m);
    scores[i] = e;
    lsum += e;
  }
  #pragma unroll
  for (int off = 32; off; off >>= 1) lsum += __shfl_xor(lsum, off);
  __syncthreads();
  if (lane == 0) wred[wid] = lsum;
  __syncthreads();
  if (tid == 0) Sshared = wred[0] + wred[1] + wred[2] + wred[3];

  float acc = 0.f;
  for (int i = wid; i < cnt; i += 4) {
    float p = scores[i];
    const float* vr = vb + (size_t)ls[i] * C_ + h * HD_;
    acc = fmaf(p, vr[lane], acc);
  }
  accb[wid][lane] = acc;
  __syncthreads();
  if (tid < 64) {
    float tot = accb[0][tid] + accb[1][tid] + accb[2][tid] + accb[3][tid];
    ctx[(size_t)q * C_ + h * HD_ + tid] = tot / Sshared;
  }
}

// ---------------------------------------------------------------------------
extern "C" void kernel_launch(void* const* d_in, const int* in_sizes, int n_in,
                              void* d_out, int out_size, void* d_ws, size_t ws_size,
                              hipStream_t stream) {
  const float* x     = (const float*)d_in[0];
  const float* masks = (const float*)d_in[1];
  const float* Wq    = (const float*)d_in[2];
  const float* bq    = (const float*)d_in[3];
  const float* Wk    = (const float*)d_in[4];
  const float* bk    = (const float*)d_in[5];
  const float* Wv    = (const float*)d_in[6];
  const float* bv    = (const float*)d_in[7];
  const float* Wc    = (const float*)d_in[8];
  const float* bc    = (const float*)d_in[9];
  float* out = (float*)d_out;

  char* p = (char*)d_ws;
  auto alloc = [&](size_t bytes) {
    char* r = p;
    p += (bytes + 255) & ~(size_t)255;
    return r;
  };
  float* msig  = (float*)alloc((size_t)Q_ * HW_ * 4);
  float* w     = (float*)alloc(1024);
  float* meanf = (float*)alloc((size_t)Q_ * C_ * 4);
  float* qbuf  = (float*)alloc((size_t)Q_ * C_ * 4);
  float* ctx   = (float*)alloc((size_t)Q_ * C_ * 4);
  float* partial = (float*)alloc((size_t)KSPLIT * 256 * C_ * 4);
  int*   cnt   = (int*)alloc(1024);
  int*   idxg  = (int*)alloc((size_t)Q_ * CAP * 4);
  unsigned short* msigbf = (unsigned short*)alloc((size_t)256 * HW_ * 2);
  unsigned short* xbf    = (unsigned short*)alloc((size_t)C_ * HW_ * 2);
  unsigned short* seqbf  = (unsigned short*)alloc((size_t)L_ * C_ * 2);
  unsigned short* wkbf   = (unsigned short*)alloc((size_t)C_ * C_ * 2);
  unsigned short* wvbf   = (unsigned short*)alloc((size_t)C_ * C_ * 2);
  float* kbuf  = (float*)alloc((size_t)L_ * C_ * 4);
  float* vbuf  = (float*)alloc((size_t)L_ * C_ * 4);

  k_sigmoid_w<<<256, 256, 0, stream>>>(masks, msig, msigbf, w);
  k_compact<<<Q_, 256, 0, stream>>>(msig, cnt, idxg);
  k_xcast<<<dim3(HW_ / 32, C_ / 32), dim3(32, 8), 0, stream>>>(x, xbf, seqbf);
  k_cast<<<512, 256, 0, stream>>>(Wk, wkbf, C_ * C_);
  k_cast<<<512, 256, 0, stream>>>(Wv, wvbf, C_ * C_);
  // mean: split-K MFMA + reduce
  k_gemm_meank<<<dim3(C_ / GBN, 2, KSPLIT), 256, 0, stream>>>(msigbf, xbf, partial);
  k_mean_reduce<<<Q_, 256, 0, stream>>>(partial, w, meanf, seqbf);
  // Q projection (fp32, small)
  k_gemm_abt<<<dim3(C_ / BN, (Q_ + BM - 1) / BM), 256, 0, stream>>>(
      meanf, Wq, bq, qbuf, Q_, C_, C_);
  // K, V projections (bf16 MFMA)
  k_gemm_bf<<<dim3(C_ / GBN, (L_ + GBM - 1) / GBM), 256, 0, stream>>>(
      seqbf, wkbf, bk, kbuf, L_, C_);
  k_gemm_bf<<<dim3(C_ / GBN, (L_ + GBM - 1) / GBM), 256, 0, stream>>>(
      seqbf, wvbf, bv, vbuf, L_, C_);
  // sparse attention
  k_sparse_attn<<<dim3(Q_, NH_), 256, 0, stream>>>(qbuf, kbuf, vbuf, cnt, idxg, ctx);
  // output projection (fp32, small)
  k_gemm_abt<<<dim3(C_ / BN, (Q_ + BM - 1) / BM), 256, 0, stream>>>(
      ctx, Wc, bc, out, Q_, C_, C_);
}

// Round 5
// 496.148 us; speedup vs baseline: 8.5430x; 1.1423x over previous
//
#include <hip/hip_runtime.h>
#include <math.h>

#define HW_  16384
#define Q_   200
#define C_   1024
#define L_   16584   // Q_ + HW_
#define NH_  16
#define HD_  64
#define CAP  512
#define KSPLIT 8
#define KCH  (HW_ / KSPLIT)   // 2048

typedef __attribute__((ext_vector_type(8))) __bf16 bf16x8;
typedef __attribute__((ext_vector_type(8))) unsigned short u16x8;
typedef __attribute__((ext_vector_type(4))) float f32x4;

__device__ inline unsigned short f2bf(float f) {
  unsigned int u = __float_as_uint(f);
  u += 0x7fff + ((u >> 16) & 1);   // round-to-nearest-even
  return (unsigned short)(u >> 16);
}
__device__ inline float bf2f(unsigned short u) {
  return __uint_as_float((unsigned int)u << 16);
}

// ---------------------------------------------------------------------------
// sigmoid(masks) -> msig fp32 + msigbf bf16 (rows >= Q_ zeroed); w[q] = row sum
__global__ __launch_bounds__(256) void k_sigmoid_w(const float* __restrict__ masks,
                                                   float* __restrict__ msig,
                                                   unsigned short* __restrict__ msigbf,
                                                   float* __restrict__ w) {
  int q = blockIdx.x;
  int tid = threadIdx.x;
  unsigned short* obf = msigbf + (size_t)q * HW_;
  if (q >= Q_) {
    for (int i = tid; i < HW_; i += 256) obf[i] = 0;
    return;
  }
  const float* mrow = masks + (size_t)q * HW_;
  float* orow = msig + (size_t)q * HW_;
  float s = 0.f;
  for (int i = tid; i < HW_; i += 256) {
    float v = mrow[i];
    float sg = 1.f / (1.f + expf(-v));
    orow[i] = sg;
    obf[i] = f2bf(sg);
    s += sg;
  }
  __shared__ float red[256];
  red[tid] = s;
  __syncthreads();
  for (int off = 128; off > 0; off >>= 1) {
    if (tid < off) red[tid] += red[tid + off];
    __syncthreads();
  }
  if (tid == 0) w[q] = red[0];
}

// ---------------------------------------------------------------------------
// Deterministic per-query compaction of allowed pixel indices.
__global__ __launch_bounds__(256) void k_compact(const float* __restrict__ msig,
                                                 int* __restrict__ cnt,
                                                 int* __restrict__ idxg) {
  int q = blockIdx.x;
  int tid = threadIdx.x;
  const float* mrow = msig + (size_t)q * HW_;
  const int CHUNK = HW_ / 256;  // 64
  int base = tid * CHUNK;
  int my = 0;
  for (int j = 0; j < CHUNK; j++) my += (mrow[base + j] > 0.9f) ? 1 : 0;
  __shared__ int sc[256];
  sc[tid] = my;
  __syncthreads();
  for (int off = 1; off < 256; off <<= 1) {
    int v = sc[tid];
    int add = (tid >= off) ? sc[tid - off] : 0;
    __syncthreads();
    sc[tid] = v + add;
    __syncthreads();
  }
  int excl = sc[tid] - my;
  int total = sc[255];
  int* orow = idxg + (size_t)q * CAP;
  int off = 1 + excl;  // slot 0 = self
  for (int j = 0; j < CHUNK; j++) {
    if (mrow[base + j] > 0.9f) {
      if (off < CAP) orow[off] = Q_ + base + j;
      off++;
    }
  }
  if (tid == 0) {
    orow[0] = q;
    int c = 1 + total;
    cnt[q] = c < CAP ? c : CAP;
  }
}

// ---------------------------------------------------------------------------
// x [C][HW] fp32 -> xbf [C][HW] bf16 (same layout) + seqbf pixel rows (transposed)
__global__ __launch_bounds__(256) void k_xcast(const float* __restrict__ x,
                                               unsigned short* __restrict__ xbf,
                                               unsigned short* __restrict__ seqbf) {
  __shared__ float t[32][33];
  int l0 = blockIdx.x * 32, c0 = blockIdx.y * 32;
  int tx = threadIdx.x, ty = threadIdx.y;  // (32,8)
  #pragma unroll
  for (int i = 0; i < 32; i += 8) {
    float v = x[(size_t)(c0 + ty + i) * HW_ + l0 + tx];
    t[ty + i][tx] = v;
    xbf[(size_t)(c0 + ty + i) * HW_ + l0 + tx] = f2bf(v);
  }
  __syncthreads();
  #pragma unroll
  for (int i = 0; i < 32; i += 8)
    seqbf[(size_t)(Q_ + l0 + ty + i) * C_ + c0 + tx] = f2bf(t[tx][ty + i]);
}

// ---------------------------------------------------------------------------
__global__ __launch_bounds__(256) void k_cast(const float* __restrict__ in,
                                              unsigned short* __restrict__ out, int n) {
  int stride = gridDim.x * 256;
  for (int i = blockIdx.x * 256 + threadIdx.x; i < n; i += stride)
    out[i] = f2bf(in[i]);
}

// ---------------------------------------------------------------------------
// bf16 MFMA GEMM: acc = sum_k A[m][k]*B[n][k] + bias[n]; A:[M][K], B:[1024][K]
// Output: fp32 to Cf (if non-null) or bf16 to Cbf.
#define GBM 128
#define GBN 128
#define GBK 32

__global__ __launch_bounds__(256) void k_gemm_bf(const unsigned short* __restrict__ A,
                                                 const unsigned short* __restrict__ B,
                                                 const float* __restrict__ bias,
                                                 float* __restrict__ Cf,
                                                 unsigned short* __restrict__ Cbf,
                                                 int M, int K) {
  __shared__ __attribute__((aligned(16))) unsigned short As[GBM][GBK];
  __shared__ __attribute__((aligned(16))) unsigned short Bs[GBN][GBK];
  int bm = blockIdx.y * GBM, bn = blockIdx.x * GBN;
  int tid = threadIdx.x;
  int wid = tid >> 6, lane = tid & 63;
  int wr = wid >> 1, wc = wid & 1;
  int fq = lane >> 4, fr = lane & 15;
  int srow = lane >> 2;
  int scol = (lane & 3) * 8;
  f32x4 acc[4][4] = {};
  for (int k0 = 0; k0 < K; k0 += GBK) {
    __syncthreads();
    #pragma unroll
    for (int i = 0; i < 2; i++) {
      int r = wid * 32 + i * 16 + srow;
      int gA = bm + r; if (gA > M - 1) gA = M - 1;
      __builtin_amdgcn_global_load_lds(
          (const __attribute__((address_space(1))) void*)(A + (size_t)gA * K + k0 + scol),
          (__attribute__((address_space(3))) void*)((char*)&As[0][0] + (wid * 2 + i) * 1024),
          16, 0, 0);
      int gB = bn + r;
      __builtin_amdgcn_global_load_lds(
          (const __attribute__((address_space(1))) void*)(B + (size_t)gB * K + k0 + scol),
          (__attribute__((address_space(3))) void*)((char*)&Bs[0][0] + (wid * 2 + i) * 1024),
          16, 0, 0);
    }
    __syncthreads();
    bf16x8 af[4], bfr[4];
    #pragma unroll
    for (int mi = 0; mi < 4; mi++)
      af[mi] = *(const bf16x8*)&As[wr * 64 + mi * 16 + fr][fq * 8];
    #pragma unroll
    for (int ni = 0; ni < 4; ni++)
      bfr[ni] = *(const bf16x8*)&Bs[wc * 64 + ni * 16 + fr][fq * 8];
    #pragma unroll
    for (int mi = 0; mi < 4; mi++)
      #pragma unroll
      for (int ni = 0; ni < 4; ni++)
        acc[mi][ni] = __builtin_amdgcn_mfma_f32_16x16x32_bf16(af[mi], bfr[ni], acc[mi][ni], 0, 0, 0);
  }
  #pragma unroll
  for (int ni = 0; ni < 4; ni++) {
    int n = bn + wc * 64 + ni * 16 + fr;
    float bv = bias ? bias[n] : 0.f;
    #pragma unroll
    for (int mi = 0; mi < 4; mi++)
      #pragma unroll
      for (int j = 0; j < 4; j++) {
        int m = bm + wr * 64 + mi * 16 + fq * 4 + j;
        if (m < M) {
          float v = acc[mi][ni][j] + bv;
          if (Cf) Cf[(size_t)m * C_ + n] = v;
          else    Cbf[(size_t)m * C_ + n] = f2bf(v);
        }
      }
  }
}

// ---------------------------------------------------------------------------
// Split-K mean GEMM: A = msigbf [256][HW_], B = xbf [1024][HW_]; z = K-chunk.
__global__ __launch_bounds__(256) void k_gemm_meank(const unsigned short* __restrict__ A,
                                                    const unsigned short* __restrict__ B,
                                                    float* __restrict__ partial) {
  __shared__ __attribute__((aligned(16))) unsigned short As[GBM][GBK];
  __shared__ __attribute__((aligned(16))) unsigned short Bs[GBN][GBK];
  int bm = blockIdx.y * GBM, bn = blockIdx.x * GBN;
  int kc = blockIdx.z;
  int tid = threadIdx.x;
  int wid = tid >> 6, lane = tid & 63;
  int wr = wid >> 1, wc = wid & 1;
  int fq = lane >> 4, fr = lane & 15;
  int srow = lane >> 2;
  int scol = (lane & 3) * 8;
  f32x4 acc[4][4] = {};
  int kbeg = kc * KCH, kend = kbeg + KCH;
  for (int k0 = kbeg; k0 < kend; k0 += GBK) {
    __syncthreads();
    #pragma unroll
    for (int i = 0; i < 2; i++) {
      int r = wid * 32 + i * 16 + srow;
      __builtin_amdgcn_global_load_lds(
          (const __attribute__((address_space(1))) void*)(A + (size_t)(bm + r) * HW_ + k0 + scol),
          (__attribute__((address_space(3))) void*)((char*)&As[0][0] + (wid * 2 + i) * 1024),
          16, 0, 0);
      __builtin_amdgcn_global_load_lds(
          (const __attribute__((address_space(1))) void*)(B + (size_t)(bn + r) * HW_ + k0 + scol),
          (__attribute__((address_space(3))) void*)((char*)&Bs[0][0] + (wid * 2 + i) * 1024),
          16, 0, 0);
    }
    __syncthreads();
    bf16x8 af[4], bfr[4];
    #pragma unroll
    for (int mi = 0; mi < 4; mi++)
      af[mi] = *(const bf16x8*)&As[wr * 64 + mi * 16 + fr][fq * 8];
    #pragma unroll
    for (int ni = 0; ni < 4; ni++)
      bfr[ni] = *(const bf16x8*)&Bs[wc * 64 + ni * 16 + fr][fq * 8];
    #pragma unroll
    for (int mi = 0; mi < 4; mi++)
      #pragma unroll
      for (int ni = 0; ni < 4; ni++)
        acc[mi][ni] = __builtin_amdgcn_mfma_f32_16x16x32_bf16(af[mi], bfr[ni], acc[mi][ni], 0, 0, 0);
  }
  #pragma unroll
  for (int ni = 0; ni < 4; ni++) {
    int n = bn + wc * 64 + ni * 16 + fr;
    #pragma unroll
    for (int mi = 0; mi < 4; mi++)
      #pragma unroll
      for (int j = 0; j < 4; j++) {
        int m = bm + wr * 64 + mi * 16 + fq * 4 + j;
        partial[((size_t)kc * 256 + m) * C_ + n] = acc[mi][ni][j];
      }
  }
}

// ---------------------------------------------------------------------------
__global__ __launch_bounds__(256) void k_mean_reduce(const float* __restrict__ partial,
                                                     const float* __restrict__ w,
                                                     float* __restrict__ meanf,
                                                     unsigned short* __restrict__ seqbf) {
  int m = blockIdx.x;  // 0..Q_-1
  float rs = 1.f / (w[m] + 0.001f);
  for (int n = threadIdx.x; n < C_; n += 256) {
    float s = 0.f;
    #pragma unroll
    for (int kc = 0; kc < KSPLIT; kc++)
      s += partial[((size_t)kc * 256 + m) * C_ + n];
    s *= rs;
    meanf[(size_t)m * C_ + n] = s;
    seqbf[(size_t)m * C_ + n] = f2bf(s);
  }
}

// ---------------------------------------------------------------------------
// fp32 GEMM (A @ B^T + bias) for small M (Q / out projections).
#define BM 64
#define BN 64
#define BK 16
#define LDT 68

__global__ __launch_bounds__(256) void k_gemm_abt(const float* __restrict__ A,
                                                  const float* __restrict__ B,
                                                  const float* __restrict__ bias,
                                                  float* __restrict__ Cm,
                                                  int M, int N, int K) {
  __shared__ float As[BK][LDT];
  __shared__ float Bs[BK][LDT];
  int bm = blockIdx.y * BM, bn = blockIdx.x * BN;
  int tid = threadIdx.x;
  int lm = tid >> 2;
  int lk = (tid & 3) << 2;
  int r0 = (tid >> 4) << 2;
  int c0 = (tid & 15) << 2;
  float acc[4][4] = {};
  const float* Aload = A + (size_t)(bm + lm) * K + lk;
  const float* Bload = B + (size_t)(bn + lm) * K + lk;
  bool aok = (bm + lm) < M;
  for (int k0 = 0; k0 < K; k0 += BK) {
    float4 av = make_float4(0.f, 0.f, 0.f, 0.f);
    if (aok) av = *(const float4*)(Aload + k0);
    float4 bv = *(const float4*)(Bload + k0);
    __syncthreads();
    As[lk + 0][lm] = av.x; As[lk + 1][lm] = av.y;
    As[lk + 2][lm] = av.z; As[lk + 3][lm] = av.w;
    Bs[lk + 0][lm] = bv.x; Bs[lk + 1][lm] = bv.y;
    Bs[lk + 2][lm] = bv.z; Bs[lk + 3][lm] = bv.w;
    __syncthreads();
    #pragma unroll
    for (int kk = 0; kk < BK; kk++) {
      float4 a4 = *(const float4*)&As[kk][r0];
      float4 b4 = *(const float4*)&Bs[kk][c0];
      float a[4] = {a4.x, a4.y, a4.z, a4.w};
      float b[4] = {b4.x, b4.y, b4.z, b4.w};
      #pragma unroll
      for (int i = 0; i < 4; i++)
        #pragma unroll
        for (int j = 0; j < 4; j++)
          acc[i][j] = fmaf(a[i], b[j], acc[i][j]);
    }
  }
  #pragma unroll
  for (int i = 0; i < 4; i++) {
    int m = bm + r0 + i;
    if (m >= M) continue;
    #pragma unroll
    for (int j = 0; j < 4; j++) {
      int n = bn + c0 + j;
      float v = acc[i][j];
      if (bias) v += bias[n];
      Cm[(size_t)m * N + n] = v;
    }
  }
}

// ---------------------------------------------------------------------------
// Sparse gather attention, bf16 K/V. Block = (q, h).
__global__ __launch_bounds__(256) void k_sparse_attn(const float* __restrict__ qb,
                                                     const unsigned short* __restrict__ kb,
                                                     const unsigned short* __restrict__ vb,
                                                     const int* __restrict__ cnt_g,
                                                     const int* __restrict__ idxg,
                                                     float* __restrict__ ctx) {
  int q = blockIdx.x;
  int h = blockIdx.y;
  int tid = threadIdx.x;
  int lane = tid & 63, wid = tid >> 6;

  __shared__ float qs[64];
  __shared__ float scores[CAP];
  __shared__ int   ls[CAP];
  __shared__ float wred[4];
  __shared__ float accb[4][64];
  __shared__ float Sshared;

  int cnt = cnt_g[q];
  const int* myidx = idxg + (size_t)q * CAP;
  if (tid < 64) qs[tid] = qb[(size_t)q * C_ + h * HD_ + tid] * 0.125f;
  __syncthreads();

  // scores (bf16 K, fp32 accumulate)
  for (int i = tid; i < cnt; i += 256) {
    int l = myidx[i];
    ls[i] = l;
    const u16x8* kr = (const u16x8*)(kb + (size_t)l * C_ + h * HD_);
    float s = 0.f;
    #pragma unroll
    for (int v8 = 0; v8 < 8; v8++) {
      u16x8 kv = kr[v8];
      #pragma unroll
      for (int e = 0; e < 8; e++) s = fmaf(qs[v8 * 8 + e], bf2f(kv[e]), s);
    }
    scores[i] = s;
  }
  __syncthreads();

  float lm = -INFINITY;
  for (int i = tid; i < cnt; i += 256) lm = fmaxf(lm, scores[i]);
  #pragma unroll
  for (int off = 32; off; off >>= 1) lm = fmaxf(lm, __shfl_xor(lm, off));
  if (lane == 0) wred[wid] = lm;
  __syncthreads();
  float m = fmaxf(fmaxf(wred[0], wred[1]), fmaxf(wred[2], wred[3]));

  float lsum = 0.f;
  for (int i = tid; i < cnt; i += 256) {
    float e = expf(scores[i] - m);
    scores[i] = e;
    lsum += e;
  }
  #pragma unroll
  for (int off = 32; off; off >>= 1) lsum += __shfl_xor(lsum, off);
  __syncthreads();
  if (lane == 0) wred[wid] = lsum;
  __syncthreads();
  if (tid == 0) Sshared = wred[0] + wred[1] + wred[2] + wred[3];

  // PV: wave w takes i = w, w+4, ...; lane owns dim d = lane (bf16 V)
  float acc = 0.f;
  for (int i = wid; i < cnt; i += 4) {
    float p = scores[i];
    acc = fmaf(p, bf2f(vb[(size_t)ls[i] * C_ + h * HD_ + lane]), acc);
  }
  accb[wid][lane] = acc;
  __syncthreads();
  if (tid < 64) {
    float tot = accb[0][tid] + accb[1][tid] + accb[2][tid] + accb[3][tid];
    ctx[(size_t)q * C_ + h * HD_ + tid] = tot / Sshared;
  }
}

// ---------------------------------------------------------------------------
extern "C" void kernel_launch(void* const* d_in, const int* in_sizes, int n_in,
                              void* d_out, int out_size, void* d_ws, size_t ws_size,
                              hipStream_t stream) {
  const float* x     = (const float*)d_in[0];
  const float* masks = (const float*)d_in[1];
  const float* Wq    = (const float*)d_in[2];
  const float* bq    = (const float*)d_in[3];
  const float* Wk    = (const float*)d_in[4];
  const float* bk    = (const float*)d_in[5];
  const float* Wv    = (const float*)d_in[6];
  const float* bv    = (const float*)d_in[7];
  const float* Wc    = (const float*)d_in[8];
  const float* bc    = (const float*)d_in[9];
  float* out = (float*)d_out;

  char* p = (char*)d_ws;
  auto alloc = [&](size_t bytes) {
    char* r = p;
    p += (bytes + 255) & ~(size_t)255;
    return r;
  };
  float* msig  = (float*)alloc((size_t)Q_ * HW_ * 4);
  float* w     = (float*)alloc(1024);
  float* meanf = (float*)alloc((size_t)Q_ * C_ * 4);
  float* qbuf  = (float*)alloc((size_t)Q_ * C_ * 4);
  float* ctx   = (float*)alloc((size_t)Q_ * C_ * 4);
  float* partial = (float*)alloc((size_t)KSPLIT * 256 * C_ * 4);
  int*   cnt   = (int*)alloc(1024);
  int*   idxg  = (int*)alloc((size_t)Q_ * CAP * 4);
  unsigned short* msigbf = (unsigned short*)alloc((size_t)256 * HW_ * 2);
  unsigned short* xbf    = (unsigned short*)alloc((size_t)C_ * HW_ * 2);
  unsigned short* seqbf  = (unsigned short*)alloc((size_t)L_ * C_ * 2);
  unsigned short* wkbf   = (unsigned short*)alloc((size_t)C_ * C_ * 2);
  unsigned short* wvbf   = (unsigned short*)alloc((size_t)C_ * C_ * 2);
  unsigned short* kbuf   = (unsigned short*)alloc((size_t)L_ * C_ * 2);
  unsigned short* vbuf   = (unsigned short*)alloc((size_t)L_ * C_ * 2);

  k_sigmoid_w<<<256, 256, 0, stream>>>(masks, msig, msigbf, w);
  k_compact<<<Q_, 256, 0, stream>>>(msig, cnt, idxg);
  k_xcast<<<dim3(HW_ / 32, C_ / 32), dim3(32, 8), 0, stream>>>(x, xbf, seqbf);
  k_cast<<<512, 256, 0, stream>>>(Wk, wkbf, C_ * C_);
  k_cast<<<512, 256, 0, stream>>>(Wv, wvbf, C_ * C_);
  // mean: split-K MFMA + reduce
  k_gemm_meank<<<dim3(C_ / GBN, 2, KSPLIT), 256, 0, stream>>>(msigbf, xbf, partial);
  k_mean_reduce<<<Q_, 256, 0, stream>>>(partial, w, meanf, seqbf);
  // Q projection (fp32, small)
  k_gemm_abt<<<dim3(C_ / BN, (Q_ + BM - 1) / BM), 256, 0, stream>>>(
      meanf, Wq, bq, qbuf, Q_, C_, C_);
  // K, V projections (bf16 MFMA, bf16 outputs)
  k_gemm_bf<<<dim3(C_ / GBN, (L_ + GBM - 1) / GBM), 256, 0, stream>>>(
      seqbf, wkbf, bk, nullptr, kbuf, L_, C_);
  k_gemm_bf<<<dim3(C_ / GBN, (L_ + GBM - 1) / GBM), 256, 0, stream>>>(
      seqbf, wvbf, bv, nullptr, vbuf, L_, C_);
  // sparse attention
  k_sparse_attn<<<dim3(Q_, NH_), 256, 0, stream>>>(qbuf, kbuf, vbuf, cnt, idxg, ctx);
  // output projection (fp32, small)
  k_gemm_abt<<<dim3(C_ / BN, (Q_ + BM - 1) / BM), 256, 0, stream>>>(
      ctx, Wc, bc, out, Q_, C_, C_);
}

// Round 6
// 390.260 us; speedup vs baseline: 10.8609x; 1.2713x over previous
//
#include <hip/hip_runtime.h>
#include <math.h>

#define HW_  16384
#define Q_   200
#define C_   1024
#define L_   16584   // Q_ + HW_
#define NH_  16
#define HD_  64
#define CAP  512
#define KSPLIT 8
#define KCH  (HW_ / KSPLIT)   // 2048
#define ASPLIT 4
#define SK   8                // split-K for small projections (K=1024 -> 128/chunk)

typedef __attribute__((ext_vector_type(8))) __bf16 bf16x8;
typedef __attribute__((ext_vector_type(8))) unsigned short u16x8;
typedef __attribute__((ext_vector_type(4))) float f32x4;

__device__ inline unsigned short f2bf(float f) {
  unsigned int u = __float_as_uint(f);
  u += 0x7fff + ((u >> 16) & 1);   // round-to-nearest-even
  return (unsigned short)(u >> 16);
}
__device__ inline float bf2f(unsigned short u) {
  return __uint_as_float((unsigned int)u << 16);
}

// ---------------------------------------------------------------------------
// sigmoid(masks) -> msig fp32 + msigbf bf16 (rows >= Q_ zeroed); w[q] = row sum
__global__ __launch_bounds__(256) void k_sigmoid_w(const float* __restrict__ masks,
                                                   float* __restrict__ msig,
                                                   unsigned short* __restrict__ msigbf,
                                                   float* __restrict__ w) {
  int q = blockIdx.x;
  int tid = threadIdx.x;
  unsigned short* obf = msigbf + (size_t)q * HW_;
  if (q >= Q_) {
    for (int i = tid; i < HW_; i += 256) obf[i] = 0;
    return;
  }
  const float* mrow = masks + (size_t)q * HW_;
  float* orow = msig + (size_t)q * HW_;
  float s = 0.f;
  for (int i = tid; i < HW_; i += 256) {
    float v = mrow[i];
    float sg = 1.f / (1.f + expf(-v));
    orow[i] = sg;
    obf[i] = f2bf(sg);
    s += sg;
  }
  __shared__ float red[256];
  red[tid] = s;
  __syncthreads();
  for (int off = 128; off > 0; off >>= 1) {
    if (tid < off) red[tid] += red[tid + off];
    __syncthreads();
  }
  if (tid == 0) w[q] = red[0];
}

// ---------------------------------------------------------------------------
// Deterministic per-query compaction of allowed pixel indices.
__global__ __launch_bounds__(256) void k_compact(const float* __restrict__ msig,
                                                 int* __restrict__ cnt,
                                                 int* __restrict__ idxg) {
  int q = blockIdx.x;
  int tid = threadIdx.x;
  const float* mrow = msig + (size_t)q * HW_;
  const int CHUNK = HW_ / 256;  // 64
  int base = tid * CHUNK;
  int my = 0;
  for (int j = 0; j < CHUNK; j++) my += (mrow[base + j] > 0.9f) ? 1 : 0;
  __shared__ int sc[256];
  sc[tid] = my;
  __syncthreads();
  for (int off = 1; off < 256; off <<= 1) {
    int v = sc[tid];
    int add = (tid >= off) ? sc[tid - off] : 0;
    __syncthreads();
    sc[tid] = v + add;
    __syncthreads();
  }
  int excl = sc[tid] - my;
  int total = sc[255];
  int* orow = idxg + (size_t)q * CAP;
  int off = 1 + excl;  // slot 0 = self
  for (int j = 0; j < CHUNK; j++) {
    if (mrow[base + j] > 0.9f) {
      if (off < CAP) orow[off] = Q_ + base + j;
      off++;
    }
  }
  if (tid == 0) {
    orow[0] = q;
    int c = 1 + total;
    cnt[q] = c < CAP ? c : CAP;
  }
}

// ---------------------------------------------------------------------------
// x [C][HW] fp32 -> xbf [C][HW] bf16 (same layout) + seqbf pixel rows (transposed)
__global__ __launch_bounds__(256) void k_xcast(const float* __restrict__ x,
                                               unsigned short* __restrict__ xbf,
                                               unsigned short* __restrict__ seqbf) {
  __shared__ float t[32][33];
  int l0 = blockIdx.x * 32, c0 = blockIdx.y * 32;
  int tx = threadIdx.x, ty = threadIdx.y;  // (32,8)
  #pragma unroll
  for (int i = 0; i < 32; i += 8) {
    float v = x[(size_t)(c0 + ty + i) * HW_ + l0 + tx];
    t[ty + i][tx] = v;
    xbf[(size_t)(c0 + ty + i) * HW_ + l0 + tx] = f2bf(v);
  }
  __syncthreads();
  #pragma unroll
  for (int i = 0; i < 32; i += 8)
    seqbf[(size_t)(Q_ + l0 + ty + i) * C_ + c0 + tx] = f2bf(t[tx][ty + i]);
}

// ---------------------------------------------------------------------------
__global__ __launch_bounds__(256) void k_cast(const float* __restrict__ in,
                                              unsigned short* __restrict__ out, int n) {
  int stride = gridDim.x * 256;
  for (int i = blockIdx.x * 256 + threadIdx.x; i < n; i += stride)
    out[i] = f2bf(in[i]);
}

// ---------------------------------------------------------------------------
// bf16 MFMA GEMM: C[m][n] = sum_k A[m][k]*B[n][k] + bias[n]; bf16 output.
#define GBM 128
#define GBN 128
#define GBK 32

__global__ __launch_bounds__(256) void k_gemm_bf(const unsigned short* __restrict__ A,
                                                 const unsigned short* __restrict__ B,
                                                 const float* __restrict__ bias,
                                                 unsigned short* __restrict__ Cbf,
                                                 int M, int K) {
  __shared__ __attribute__((aligned(16))) unsigned short As[GBM][GBK];
  __shared__ __attribute__((aligned(16))) unsigned short Bs[GBN][GBK];
  int bm = blockIdx.y * GBM, bn = blockIdx.x * GBN;
  int tid = threadIdx.x;
  int wid = tid >> 6, lane = tid & 63;
  int wr = wid >> 1, wc = wid & 1;
  int fq = lane >> 4, fr = lane & 15;
  int srow = lane >> 2;
  int scol = (lane & 3) * 8;
  f32x4 acc[4][4] = {};
  for (int k0 = 0; k0 < K; k0 += GBK) {
    __syncthreads();
    #pragma unroll
    for (int i = 0; i < 2; i++) {
      int r = wid * 32 + i * 16 + srow;
      int gA = bm + r; if (gA > M - 1) gA = M - 1;
      __builtin_amdgcn_global_load_lds(
          (const __attribute__((address_space(1))) void*)(A + (size_t)gA * K + k0 + scol),
          (__attribute__((address_space(3))) void*)((char*)&As[0][0] + (wid * 2 + i) * 1024),
          16, 0, 0);
      int gB = bn + r;
      __builtin_amdgcn_global_load_lds(
          (const __attribute__((address_space(1))) void*)(B + (size_t)gB * K + k0 + scol),
          (__attribute__((address_space(3))) void*)((char*)&Bs[0][0] + (wid * 2 + i) * 1024),
          16, 0, 0);
    }
    __syncthreads();
    bf16x8 af[4], bfr[4];
    #pragma unroll
    for (int mi = 0; mi < 4; mi++)
      af[mi] = *(const bf16x8*)&As[wr * 64 + mi * 16 + fr][fq * 8];
    #pragma unroll
    for (int ni = 0; ni < 4; ni++)
      bfr[ni] = *(const bf16x8*)&Bs[wc * 64 + ni * 16 + fr][fq * 8];
    #pragma unroll
    for (int mi = 0; mi < 4; mi++)
      #pragma unroll
      for (int ni = 0; ni < 4; ni++)
        acc[mi][ni] = __builtin_amdgcn_mfma_f32_16x16x32_bf16(af[mi], bfr[ni], acc[mi][ni], 0, 0, 0);
  }
  #pragma unroll
  for (int ni = 0; ni < 4; ni++) {
    int n = bn + wc * 64 + ni * 16 + fr;
    float bv = bias ? bias[n] : 0.f;
    #pragma unroll
    for (int mi = 0; mi < 4; mi++)
      #pragma unroll
      for (int j = 0; j < 4; j++) {
        int m = bm + wr * 64 + mi * 16 + fq * 4 + j;
        if (m < M) Cbf[(size_t)m * C_ + n] = f2bf(acc[mi][ni][j] + bv);
      }
  }
}

// ---------------------------------------------------------------------------
// Split-K mean GEMM: A = msigbf [256][HW_], B = xbf [1024][HW_]; z = K-chunk.
__global__ __launch_bounds__(256) void k_gemm_meank(const unsigned short* __restrict__ A,
                                                    const unsigned short* __restrict__ B,
                                                    float* __restrict__ partial) {
  __shared__ __attribute__((aligned(16))) unsigned short As[GBM][GBK];
  __shared__ __attribute__((aligned(16))) unsigned short Bs[GBN][GBK];
  int bm = blockIdx.y * GBM, bn = blockIdx.x * GBN;
  int kc = blockIdx.z;
  int tid = threadIdx.x;
  int wid = tid >> 6, lane = tid & 63;
  int wr = wid >> 1, wc = wid & 1;
  int fq = lane >> 4, fr = lane & 15;
  int srow = lane >> 2;
  int scol = (lane & 3) * 8;
  f32x4 acc[4][4] = {};
  int kbeg = kc * KCH, kend = kbeg + KCH;
  for (int k0 = kbeg; k0 < kend; k0 += GBK) {
    __syncthreads();
    #pragma unroll
    for (int i = 0; i < 2; i++) {
      int r = wid * 32 + i * 16 + srow;
      __builtin_amdgcn_global_load_lds(
          (const __attribute__((address_space(1))) void*)(A + (size_t)(bm + r) * HW_ + k0 + scol),
          (__attribute__((address_space(3))) void*)((char*)&As[0][0] + (wid * 2 + i) * 1024),
          16, 0, 0);
      __builtin_amdgcn_global_load_lds(
          (const __attribute__((address_space(1))) void*)(B + (size_t)(bn + r) * HW_ + k0 + scol),
          (__attribute__((address_space(3))) void*)((char*)&Bs[0][0] + (wid * 2 + i) * 1024),
          16, 0, 0);
    }
    __syncthreads();
    bf16x8 af[4], bfr[4];
    #pragma unroll
    for (int mi = 0; mi < 4; mi++)
      af[mi] = *(const bf16x8*)&As[wr * 64 + mi * 16 + fr][fq * 8];
    #pragma unroll
    for (int ni = 0; ni < 4; ni++)
      bfr[ni] = *(const bf16x8*)&Bs[wc * 64 + ni * 16 + fr][fq * 8];
    #pragma unroll
    for (int mi = 0; mi < 4; mi++)
      #pragma unroll
      for (int ni = 0; ni < 4; ni++)
        acc[mi][ni] = __builtin_amdgcn_mfma_f32_16x16x32_bf16(af[mi], bfr[ni], acc[mi][ni], 0, 0, 0);
  }
  #pragma unroll
  for (int ni = 0; ni < 4; ni++) {
    int n = bn + wc * 64 + ni * 16 + fr;
    #pragma unroll
    for (int mi = 0; mi < 4; mi++)
      #pragma unroll
      for (int j = 0; j < 4; j++) {
        int m = bm + wr * 64 + mi * 16 + fq * 4 + j;
        partial[((size_t)kc * 256 + m) * C_ + n] = acc[mi][ni][j];
      }
  }
}

// ---------------------------------------------------------------------------
// mean = (sum of partials) / (w + 1e-3) -> seqbf rows 0..Q-1 (bf16)
__global__ __launch_bounds__(256) void k_mean_reduce(const float* __restrict__ partial,
                                                     const float* __restrict__ w,
                                                     unsigned short* __restrict__ seqbf) {
  int m = blockIdx.x;  // 0..Q_-1
  float rs = 1.f / (w[m] + 0.001f);
  for (int n = threadIdx.x; n < C_; n += 256) {
    float s = 0.f;
    #pragma unroll
    for (int kc = 0; kc < KSPLIT; kc++)
      s += partial[((size_t)kc * 256 + m) * C_ + n];
    seqbf[(size_t)m * C_ + n] = f2bf(s * rs);
  }
}

// ---------------------------------------------------------------------------
// Split-K bf16 MFMA GEMM for small-M projections. K=1024, SK chunks.
__global__ __launch_bounds__(256) void k_gemm_splitk_bf(const unsigned short* __restrict__ A,
                                                        const unsigned short* __restrict__ B,
                                                        float* __restrict__ partial,
                                                        int M, int K) {
  __shared__ __attribute__((aligned(16))) unsigned short As[GBM][GBK];
  __shared__ __attribute__((aligned(16))) unsigned short Bs[GBN][GBK];
  int bm = blockIdx.y * GBM, bn = blockIdx.x * GBN;
  int kc = blockIdx.z;
  int kchunk = K / SK;
  int tid = threadIdx.x;
  int wid = tid >> 6, lane = tid & 63;
  int wr = wid >> 1, wc = wid & 1;
  int fq = lane >> 4, fr = lane & 15;
  int srow = lane >> 2;
  int scol = (lane & 3) * 8;
  f32x4 acc[4][4] = {};
  int kbeg = kc * kchunk, kend = kbeg + kchunk;
  for (int k0 = kbeg; k0 < kend; k0 += GBK) {
    __syncthreads();
    #pragma unroll
    for (int i = 0; i < 2; i++) {
      int r = wid * 32 + i * 16 + srow;
      int gA = bm + r; if (gA > M - 1) gA = M - 1;
      __builtin_amdgcn_global_load_lds(
          (const __attribute__((address_space(1))) void*)(A + (size_t)gA * K + k0 + scol),
          (__attribute__((address_space(3))) void*)((char*)&As[0][0] + (wid * 2 + i) * 1024),
          16, 0, 0);
      __builtin_amdgcn_global_load_lds(
          (const __attribute__((address_space(1))) void*)(B + (size_t)(bn + r) * K + k0 + scol),
          (__attribute__((address_space(3))) void*)((char*)&Bs[0][0] + (wid * 2 + i) * 1024),
          16, 0, 0);
    }
    __syncthreads();
    bf16x8 af[4], bfr[4];
    #pragma unroll
    for (int mi = 0; mi < 4; mi++)
      af[mi] = *(const bf16x8*)&As[wr * 64 + mi * 16 + fr][fq * 8];
    #pragma unroll
    for (int ni = 0; ni < 4; ni++)
      bfr[ni] = *(const bf16x8*)&Bs[wc * 64 + ni * 16 + fr][fq * 8];
    #pragma unroll
    for (int mi = 0; mi < 4; mi++)
      #pragma unroll
      for (int ni = 0; ni < 4; ni++)
        acc[mi][ni] = __builtin_amdgcn_mfma_f32_16x16x32_bf16(af[mi], bfr[ni], acc[mi][ni], 0, 0, 0);
  }
  #pragma unroll
  for (int ni = 0; ni < 4; ni++) {
    int n = bn + wc * 64 + ni * 16 + fr;
    #pragma unroll
    for (int mi = 0; mi < 4; mi++)
      #pragma unroll
      for (int j = 0; j < 4; j++) {
        int m = bm + wr * 64 + mi * 16 + fq * 4 + j;
        partial[((size_t)kc * 256 + m) * C_ + n] = acc[mi][ni][j];
      }
  }
}

// ---------------------------------------------------------------------------
__global__ __launch_bounds__(256) void k_splitk_reduce(const float* __restrict__ partial,
                                                       const float* __restrict__ bias,
                                                       float* __restrict__ outf) {
  int m = blockIdx.x;
  for (int n = threadIdx.x; n < C_; n += 256) {
    float s = 0.f;
    #pragma unroll
    for (int kc = 0; kc < SK; kc++)
      s += partial[((size_t)kc * 256 + m) * C_ + n];
    outf[(size_t)m * C_ + n] = s + bias[n];
  }
}

// ---------------------------------------------------------------------------
// Sparse gather attention, split across ASPLIT blocks per (q,h).
__global__ __launch_bounds__(256) void k_attn_split(const float* __restrict__ qb,
                                                    const unsigned short* __restrict__ kb,
                                                    const unsigned short* __restrict__ vb,
                                                    const int* __restrict__ cnt_g,
                                                    const int* __restrict__ idxg,
                                                    float* __restrict__ pmax,
                                                    float* __restrict__ psum,
                                                    float* __restrict__ pacc) {
  int q = blockIdx.x, h = blockIdx.y, sp = blockIdx.z;
  int tid = threadIdx.x;
  int lane = tid & 63, wid = tid >> 6;

  __shared__ float qs[64];
  __shared__ float sc[CAP / ASPLIT];   // 128
  __shared__ int   ls[CAP / ASPLIT];
  __shared__ float wred[4];
  __shared__ float accb[4][64];

  int cnt = cnt_g[q];
  int cq = (cnt + ASPLIT - 1) / ASPLIT;
  int beg = sp * cq;
  int end = beg + cq; if (end > cnt) end = cnt;
  int ns = end - beg; if (ns < 0) ns = 0;

  if (tid < 64) qs[tid] = qb[(size_t)q * C_ + h * HD_ + tid] * 0.125f;
  __syncthreads();

  // scores (one row per thread; ns <= 128)
  if (tid < ns) {
    int l = idxg[(size_t)q * CAP + beg + tid];
    ls[tid] = l;
    const u16x8* kr = (const u16x8*)(kb + (size_t)l * C_ + h * HD_);
    float s = 0.f;
    #pragma unroll
    for (int v8 = 0; v8 < 8; v8++) {
      u16x8 kv = kr[v8];
      #pragma unroll
      for (int e = 0; e < 8; e++) s = fmaf(qs[v8 * 8 + e], bf2f(kv[e]), s);
    }
    sc[tid] = s;
  }
  __syncthreads();

  // local max
  float lm = (tid < ns) ? sc[tid] : -INFINITY;
  #pragma unroll
  for (int off = 32; off; off >>= 1) lm = fmaxf(lm, __shfl_xor(lm, off));
  if (lane == 0) wred[wid] = lm;
  __syncthreads();
  float m4 = fmaxf(fmaxf(wred[0], wred[1]), fmaxf(wred[2], wred[3]));

  // exp + local sum
  float e = 0.f;
  if (tid < ns) {
    e = expf(sc[tid] - m4);
    sc[tid] = e;
  }
  float lsum = e;
  #pragma unroll
  for (int off = 32; off; off >>= 1) lsum += __shfl_xor(lsum, off);
  __syncthreads();  // wred(max) reads done
  if (lane == 0) wred[wid] = lsum;
  __syncthreads();
  float S4 = wred[0] + wred[1] + wred[2] + wred[3];

  // PV over local rows
  float acc = 0.f;
  for (int j = wid; j < ns; j += 4)
    acc = fmaf(sc[j], bf2f(vb[(size_t)ls[j] * C_ + h * HD_ + lane]), acc);
  accb[wid][lane] = acc;
  __syncthreads();

  int pidx = (q * NH_ + h) * ASPLIT + sp;
  if (tid < 64)
    pacc[(size_t)pidx * 64 + tid] =
        accb[0][tid] + accb[1][tid] + accb[2][tid] + accb[3][tid];
  if (tid == 0) {
    pmax[pidx] = (ns > 0) ? m4 : -INFINITY;
    psum[pidx] = S4;
  }
}

// ---------------------------------------------------------------------------
__global__ __launch_bounds__(64) void k_attn_merge(const float* __restrict__ pmax,
                                                   const float* __restrict__ psum,
                                                   const float* __restrict__ pacc,
                                                   unsigned short* __restrict__ ctxbf) {
  int q = blockIdx.x, h = blockIdx.y;
  int d = threadIdx.x;
  int base = (q * NH_ + h) * ASPLIT;
  float M = -INFINITY;
  #pragma unroll
  for (int s = 0; s < ASPLIT; s++) M = fmaxf(M, pmax[base + s]);
  float S = 0.f, a = 0.f;
  #pragma unroll
  for (int s = 0; s < ASPLIT; s++) {
    float wgt = expf(pmax[base + s] - M);
    S += psum[base + s] * wgt;
    a += pacc[(size_t)(base + s) * 64 + d] * wgt;
  }
  ctxbf[(size_t)q * C_ + h * HD_ + d] = f2bf(a / S);
}

// ---------------------------------------------------------------------------
extern "C" void kernel_launch(void* const* d_in, const int* in_sizes, int n_in,
                              void* d_out, int out_size, void* d_ws, size_t ws_size,
                              hipStream_t stream) {
  const float* x     = (const float*)d_in[0];
  const float* masks = (const float*)d_in[1];
  const float* Wq    = (const float*)d_in[2];
  const float* bq    = (const float*)d_in[3];
  const float* Wk    = (const float*)d_in[4];
  const float* bk    = (const float*)d_in[5];
  const float* Wv    = (const float*)d_in[6];
  const float* bv    = (const float*)d_in[7];
  const float* Wc    = (const float*)d_in[8];
  const float* bc    = (const float*)d_in[9];
  float* out = (float*)d_out;

  char* p = (char*)d_ws;
  auto alloc = [&](size_t bytes) {
    char* r = p;
    p += (bytes + 255) & ~(size_t)255;
    return r;
  };
  float* msig    = (float*)alloc((size_t)Q_ * HW_ * 4);
  float* w       = (float*)alloc(1024);
  float* qbuf    = (float*)alloc((size_t)Q_ * C_ * 4);
  float* partial = (float*)alloc((size_t)KSPLIT * 256 * C_ * 4);  // reused by split-K projs
  int*   cnt     = (int*)alloc(1024);
  int*   idxg    = (int*)alloc((size_t)Q_ * CAP * 4);
  float* pmax    = (float*)alloc((size_t)Q_ * NH_ * ASPLIT * 4);
  float* psum    = (float*)alloc((size_t)Q_ * NH_ * ASPLIT * 4);
  float* pacc    = (float*)alloc((size_t)Q_ * NH_ * ASPLIT * 64 * 4);
  unsigned short* msigbf = (unsigned short*)alloc((size_t)256 * HW_ * 2);
  unsigned short* xbf    = (unsigned short*)alloc((size_t)C_ * HW_ * 2);
  unsigned short* seqbf  = (unsigned short*)alloc((size_t)L_ * C_ * 2);
  unsigned short* wkbf   = (unsigned short*)alloc((size_t)C_ * C_ * 2);
  unsigned short* wvbf   = (unsigned short*)alloc((size_t)C_ * C_ * 2);
  unsigned short* wqbf   = (unsigned short*)alloc((size_t)C_ * C_ * 2);
  unsigned short* wcbf   = (unsigned short*)alloc((size_t)C_ * C_ * 2);
  unsigned short* ctxbf  = (unsigned short*)alloc((size_t)256 * C_ * 2);
  unsigned short* kbuf   = (unsigned short*)alloc((size_t)L_ * C_ * 2);
  unsigned short* vbuf   = (unsigned short*)alloc((size_t)L_ * C_ * 2);

  k_sigmoid_w<<<256, 256, 0, stream>>>(masks, msig, msigbf, w);
  k_compact<<<Q_, 256, 0, stream>>>(msig, cnt, idxg);
  k_xcast<<<dim3(HW_ / 32, C_ / 32), dim3(32, 8), 0, stream>>>(x, xbf, seqbf);
  k_cast<<<512, 256, 0, stream>>>(Wk, wkbf, C_ * C_);
  k_cast<<<512, 256, 0, stream>>>(Wv, wvbf, C_ * C_);
  k_cast<<<512, 256, 0, stream>>>(Wq, wqbf, C_ * C_);
  k_cast<<<512, 256, 0, stream>>>(Wc, wcbf, C_ * C_);
  // mean: split-K MFMA + reduce (writes seqbf rows 0..Q-1)
  k_gemm_meank<<<dim3(C_ / GBN, 2, KSPLIT), 256, 0, stream>>>(msigbf, xbf, partial);
  k_mean_reduce<<<Q_, 256, 0, stream>>>(partial, w, seqbf);
  // Q projection (bf16 split-K)
  k_gemm_splitk_bf<<<dim3(C_ / GBN, 2, SK), 256, 0, stream>>>(seqbf, wqbf, partial, Q_, C_);
  k_splitk_reduce<<<Q_, 256, 0, stream>>>(partial, bq, qbuf);
  // K, V projections (bf16 MFMA, bf16 outputs)
  k_gemm_bf<<<dim3(C_ / GBN, (L_ + GBM - 1) / GBM), 256, 0, stream>>>(
      seqbf, wkbf, bk, kbuf, L_, C_);
  k_gemm_bf<<<dim3(C_ / GBN, (L_ + GBM - 1) / GBM), 256, 0, stream>>>(
      seqbf, wvbf, bv, vbuf, L_, C_);
  // sparse attention (split + merge -> ctxbf)
  k_attn_split<<<dim3(Q_, NH_, ASPLIT), 256, 0, stream>>>(
      qbuf, kbuf, vbuf, cnt, idxg, pmax, psum, pacc);
  k_attn_merge<<<dim3(Q_, NH_), 64, 0, stream>>>(pmax, psum, pacc, ctxbf);
  // output projection (bf16 split-K)
  k_gemm_splitk_bf<<<dim3(C_ / GBN, 2, SK), 256, 0, stream>>>(ctxbf, wcbf, partial, Q_, C_);
  k_splitk_reduce<<<Q_, 256, 0, stream>>>(partial, bc, out);
}

// Round 7
// 361.715 us; speedup vs baseline: 11.7180x; 1.0789x over previous
//
#include <hip/hip_runtime.h>
#include <math.h>

#define HW_  16384
#define Q_   200
#define C_   1024
#define L_   16584   // Q_ + HW_
#define NH_  16
#define HD_  64
#define CAP  512
#define KSPLIT 8
#define KCH  (HW_ / KSPLIT)   // 2048
#define ASPLIT 4
#define SK   8                // split-K for small projections

typedef __attribute__((ext_vector_type(8))) __bf16 bf16x8;
typedef __attribute__((ext_vector_type(8))) unsigned short u16x8;
typedef __attribute__((ext_vector_type(4))) float f32x4;

__device__ inline unsigned short f2bf(float f) {
  unsigned int u = __float_as_uint(f);
  u += 0x7fff + ((u >> 16) & 1);   // round-to-nearest-even
  return (unsigned short)(u >> 16);
}
__device__ inline float bf2f(unsigned short u) {
  return __uint_as_float((unsigned int)u << 16);
}

// ---------------------------------------------------------------------------
// sigmoid(masks) -> msig fp32 + msigbf bf16 (rows >= Q_ zeroed); w[q] = row sum
__global__ __launch_bounds__(256) void k_sigmoid_w(const float* __restrict__ masks,
                                                   float* __restrict__ msig,
                                                   unsigned short* __restrict__ msigbf,
                                                   float* __restrict__ w) {
  int q = blockIdx.x;
  int tid = threadIdx.x;
  unsigned short* obf = msigbf + (size_t)q * HW_;
  if (q >= Q_) {
    for (int i = tid; i < HW_; i += 256) obf[i] = 0;
    return;
  }
  const float* mrow = masks + (size_t)q * HW_;
  float* orow = msig + (size_t)q * HW_;
  float s = 0.f;
  for (int i = tid; i < HW_; i += 256) {
    float v = mrow[i];
    float sg = 1.f / (1.f + expf(-v));
    orow[i] = sg;
    obf[i] = f2bf(sg);
    s += sg;
  }
  __shared__ float red[256];
  red[tid] = s;
  __syncthreads();
  for (int off = 128; off > 0; off >>= 1) {
    if (tid < off) red[tid] += red[tid + off];
    __syncthreads();
  }
  if (tid == 0) w[q] = red[0];
}

// ---------------------------------------------------------------------------
// Deterministic per-query compaction of allowed pixel indices.
__global__ __launch_bounds__(256) void k_compact(const float* __restrict__ msig,
                                                 int* __restrict__ cnt,
                                                 int* __restrict__ idxg) {
  int q = blockIdx.x;
  int tid = threadIdx.x;
  const float* mrow = msig + (size_t)q * HW_;
  const int CHUNK = HW_ / 256;  // 64
  int base = tid * CHUNK;
  int my = 0;
  for (int j = 0; j < CHUNK; j++) my += (mrow[base + j] > 0.9f) ? 1 : 0;
  __shared__ int sc[256];
  sc[tid] = my;
  __syncthreads();
  for (int off = 1; off < 256; off <<= 1) {
    int v = sc[tid];
    int add = (tid >= off) ? sc[tid - off] : 0;
    __syncthreads();
    sc[tid] = v + add;
    __syncthreads();
  }
  int excl = sc[tid] - my;
  int total = sc[255];
  int* orow = idxg + (size_t)q * CAP;
  int off = 1 + excl;  // slot 0 = self
  for (int j = 0; j < CHUNK; j++) {
    if (mrow[base + j] > 0.9f) {
      if (off < CAP) orow[off] = Q_ + base + j;
      off++;
    }
  }
  if (tid == 0) {
    orow[0] = q;
    int c = 1 + total;
    cnt[q] = c < CAP ? c : CAP;
  }
}

// ---------------------------------------------------------------------------
// x [C][HW] fp32 -> xbf [C][HW] bf16 (same layout) + seqbf pixel rows (transposed)
__global__ __launch_bounds__(256) void k_xcast(const float* __restrict__ x,
                                               unsigned short* __restrict__ xbf,
                                               unsigned short* __restrict__ seqbf) {
  __shared__ float t[32][33];
  int l0 = blockIdx.x * 32, c0 = blockIdx.y * 32;
  int tx = threadIdx.x, ty = threadIdx.y;  // (32,8)
  #pragma unroll
  for (int i = 0; i < 32; i += 8) {
    float v = x[(size_t)(c0 + ty + i) * HW_ + l0 + tx];
    t[ty + i][tx] = v;
    xbf[(size_t)(c0 + ty + i) * HW_ + l0 + tx] = f2bf(v);
  }
  __syncthreads();
  #pragma unroll
  for (int i = 0; i < 32; i += 8)
    seqbf[(size_t)(Q_ + l0 + ty + i) * C_ + c0 + tx] = f2bf(t[tx][ty + i]);
}

// ---------------------------------------------------------------------------
__global__ __launch_bounds__(256) void k_cast(const float* __restrict__ in,
                                              unsigned short* __restrict__ out, int n) {
  int stride = gridDim.x * 256;
  for (int i = blockIdx.x * 256 + threadIdx.x; i < n; i += stride)
    out[i] = f2bf(in[i]);
}

#define GBM 128
#define GBN 128
#define GBK 32

// ---------------------------------------------------------------------------
// Fused K+V projection GEMM. 512 threads = 8 waves.
// Waves 0-3: K-output 128x128 tile (2x2 wave grid); waves 4-7: V-output.
// A-tile (seqbf) staged ONCE per K-step for both outputs.
// XCD-locality: blocks sharing an A-tile get consecutive IDs on one XCD.
__global__ __launch_bounds__(512) void k_gemm_kv(const unsigned short* __restrict__ A,
                                                 const unsigned short* __restrict__ Bk,
                                                 const unsigned short* __restrict__ Bv,
                                                 const float* __restrict__ bk,
                                                 const float* __restrict__ bv,
                                                 unsigned short* __restrict__ Ko,
                                                 unsigned short* __restrict__ Vo,
                                                 int M, int K) {
  __shared__ __attribute__((aligned(16))) unsigned short smem[3 * GBM * GBK]; // A | Bk | Bv
  int w = blockIdx.x;
  int nbm = gridDim.x >> 3;                  // 130
  int t = (w >> 3) + (w & 7) * nbm;          // contiguous t per XCD
  int bm = (t >> 3) * GBM;
  int bn = (t & 7) * GBN;
  int tid = threadIdx.x;
  int wid = tid >> 6, lane = tid & 63;
  int w2 = wid & 3;
  int wr = w2 >> 1, wc = w2 & 1;
  int fq = lane >> 4, fr = lane & 15;
  int srow = lane >> 2;
  int scol = (lane & 3) * 8;
  const unsigned short (*As)[GBK]  = (const unsigned short (*)[GBK])(smem);
  const unsigned short (*Bts)[GBK] = (const unsigned short (*)[GBK])(smem + (wid < 4 ? GBM * GBK : 2 * GBM * GBK));
  f32x4 acc[4][4] = {};
  for (int k0 = 0; k0 < K; k0 += GBK) {
    __syncthreads();
    #pragma unroll
    for (int i = 0; i < 3; i++) {
      int ci = wid * 3 + i;                  // 0..23 chunk of 1 KB
      const unsigned short* src;
      if (ci < 8) {
        int gA = bm + ci * 16 + srow; if (gA > M - 1) gA = M - 1;
        src = A + (size_t)gA * K + k0 + scol;
      } else if (ci < 16) {
        src = Bk + (size_t)(bn + (ci - 8) * 16 + srow) * K + k0 + scol;
      } else {
        src = Bv + (size_t)(bn + (ci - 16) * 16 + srow) * K + k0 + scol;
      }
      __builtin_amdgcn_global_load_lds(
          (const __attribute__((address_space(1))) void*)src,
          (__attribute__((address_space(3))) void*)((char*)smem + ci * 1024),
          16, 0, 0);
    }
    __syncthreads();
    bf16x8 af[4], bfr[4];
    #pragma unroll
    for (int mi = 0; mi < 4; mi++)
      af[mi] = *(const bf16x8*)&As[wr * 64 + mi * 16 + fr][fq * 8];
    #pragma unroll
    for (int ni = 0; ni < 4; ni++)
      bfr[ni] = *(const bf16x8*)&Bts[wc * 64 + ni * 16 + fr][fq * 8];
    #pragma unroll
    for (int mi = 0; mi < 4; mi++)
      #pragma unroll
      for (int ni = 0; ni < 4; ni++)
        acc[mi][ni] = __builtin_amdgcn_mfma_f32_16x16x32_bf16(af[mi], bfr[ni], acc[mi][ni], 0, 0, 0);
  }
  const float* bias = (wid < 4) ? bk : bv;
  unsigned short* Cout = (wid < 4) ? Ko : Vo;
  #pragma unroll
  for (int ni = 0; ni < 4; ni++) {
    int n = bn + wc * 64 + ni * 16 + fr;
    float bvv = bias[n];
    #pragma unroll
    for (int mi = 0; mi < 4; mi++)
      #pragma unroll
      for (int j = 0; j < 4; j++) {
        int m = bm + wr * 64 + mi * 16 + fq * 4 + j;
        if (m < M) Cout[(size_t)m * C_ + n] = f2bf(acc[mi][ni][j] + bvv);
      }
  }
}

// ---------------------------------------------------------------------------
// Split-K mean GEMM: A = msigbf [256][HW_], B = xbf [1024][HW_]; z = K-chunk.
__global__ __launch_bounds__(256) void k_gemm_meank(const unsigned short* __restrict__ A,
                                                    const unsigned short* __restrict__ B,
                                                    float* __restrict__ partial) {
  __shared__ __attribute__((aligned(16))) unsigned short As[GBM][GBK];
  __shared__ __attribute__((aligned(16))) unsigned short Bs[GBN][GBK];
  int bm = blockIdx.y * GBM, bn = blockIdx.x * GBN;
  int kc = blockIdx.z;
  int tid = threadIdx.x;
  int wid = tid >> 6, lane = tid & 63;
  int wr = wid >> 1, wc = wid & 1;
  int fq = lane >> 4, fr = lane & 15;
  int srow = lane >> 2;
  int scol = (lane & 3) * 8;
  f32x4 acc[4][4] = {};
  int kbeg = kc * KCH, kend = kbeg + KCH;
  for (int k0 = kbeg; k0 < kend; k0 += GBK) {
    __syncthreads();
    #pragma unroll
    for (int i = 0; i < 2; i++) {
      int r = wid * 32 + i * 16 + srow;
      __builtin_amdgcn_global_load_lds(
          (const __attribute__((address_space(1))) void*)(A + (size_t)(bm + r) * HW_ + k0 + scol),
          (__attribute__((address_space(3))) void*)((char*)&As[0][0] + (wid * 2 + i) * 1024),
          16, 0, 0);
      __builtin_amdgcn_global_load_lds(
          (const __attribute__((address_space(1))) void*)(B + (size_t)(bn + r) * HW_ + k0 + scol),
          (__attribute__((address_space(3))) void*)((char*)&Bs[0][0] + (wid * 2 + i) * 1024),
          16, 0, 0);
    }
    __syncthreads();
    bf16x8 af[4], bfr[4];
    #pragma unroll
    for (int mi = 0; mi < 4; mi++)
      af[mi] = *(const bf16x8*)&As[wr * 64 + mi * 16 + fr][fq * 8];
    #pragma unroll
    for (int ni = 0; ni < 4; ni++)
      bfr[ni] = *(const bf16x8*)&Bs[wc * 64 + ni * 16 + fr][fq * 8];
    #pragma unroll
    for (int mi = 0; mi < 4; mi++)
      #pragma unroll
      for (int ni = 0; ni < 4; ni++)
        acc[mi][ni] = __builtin_amdgcn_mfma_f32_16x16x32_bf16(af[mi], bfr[ni], acc[mi][ni], 0, 0, 0);
  }
  #pragma unroll
  for (int ni = 0; ni < 4; ni++) {
    int n = bn + wc * 64 + ni * 16 + fr;
    #pragma unroll
    for (int mi = 0; mi < 4; mi++)
      #pragma unroll
      for (int j = 0; j < 4; j++) {
        int m = bm + wr * 64 + mi * 16 + fq * 4 + j;
        partial[((size_t)kc * 256 + m) * C_ + n] = acc[mi][ni][j];
      }
  }
}

// ---------------------------------------------------------------------------
// mean = (sum of partials) / (w + 1e-3) -> seqbf rows 0..Q-1 (bf16)
__global__ __launch_bounds__(256) void k_mean_reduce(const float* __restrict__ partial,
                                                     const float* __restrict__ w,
                                                     unsigned short* __restrict__ seqbf) {
  int m = blockIdx.x;  // 0..Q_-1
  float rs = 1.f / (w[m] + 0.001f);
  for (int n = threadIdx.x; n < C_; n += 256) {
    float s = 0.f;
    #pragma unroll
    for (int kc = 0; kc < KSPLIT; kc++)
      s += partial[((size_t)kc * 256 + m) * C_ + n];
    seqbf[(size_t)m * C_ + n] = f2bf(s * rs);
  }
}

// ---------------------------------------------------------------------------
// Split-K bf16 MFMA GEMM for small-M projections. K=1024, SK chunks.
__global__ __launch_bounds__(256) void k_gemm_splitk_bf(const unsigned short* __restrict__ A,
                                                        const unsigned short* __restrict__ B,
                                                        float* __restrict__ partial,
                                                        int M, int K) {
  __shared__ __attribute__((aligned(16))) unsigned short As[GBM][GBK];
  __shared__ __attribute__((aligned(16))) unsigned short Bs[GBN][GBK];
  int bm = blockIdx.y * GBM, bn = blockIdx.x * GBN;
  int kc = blockIdx.z;
  int kchunk = K / SK;
  int tid = threadIdx.x;
  int wid = tid >> 6, lane = tid & 63;
  int wr = wid >> 1, wc = wid & 1;
  int fq = lane >> 4, fr = lane & 15;
  int srow = lane >> 2;
  int scol = (lane & 3) * 8;
  f32x4 acc[4][4] = {};
  int kbeg = kc * kchunk, kend = kbeg + kchunk;
  for (int k0 = kbeg; k0 < kend; k0 += GBK) {
    __syncthreads();
    #pragma unroll
    for (int i = 0; i < 2; i++) {
      int r = wid * 32 + i * 16 + srow;
      int gA = bm + r; if (gA > M - 1) gA = M - 1;
      __builtin_amdgcn_global_load_lds(
          (const __attribute__((address_space(1))) void*)(A + (size_t)gA * K + k0 + scol),
          (__attribute__((address_space(3))) void*)((char*)&As[0][0] + (wid * 2 + i) * 1024),
          16, 0, 0);
      __builtin_amdgcn_global_load_lds(
          (const __attribute__((address_space(1))) void*)(B + (size_t)(bn + r) * K + k0 + scol),
          (__attribute__((address_space(3))) void*)((char*)&Bs[0][0] + (wid * 2 + i) * 1024),
          16, 0, 0);
    }
    __syncthreads();
    bf16x8 af[4], bfr[4];
    #pragma unroll
    for (int mi = 0; mi < 4; mi++)
      af[mi] = *(const bf16x8*)&As[wr * 64 + mi * 16 + fr][fq * 8];
    #pragma unroll
    for (int ni = 0; ni < 4; ni++)
      bfr[ni] = *(const bf16x8*)&Bs[wc * 64 + ni * 16 + fr][fq * 8];
    #pragma unroll
    for (int mi = 0; mi < 4; mi++)
      #pragma unroll
      for (int ni = 0; ni < 4; ni++)
        acc[mi][ni] = __builtin_amdgcn_mfma_f32_16x16x32_bf16(af[mi], bfr[ni], acc[mi][ni], 0, 0, 0);
  }
  #pragma unroll
  for (int ni = 0; ni < 4; ni++) {
    int n = bn + wc * 64 + ni * 16 + fr;
    #pragma unroll
    for (int mi = 0; mi < 4; mi++)
      #pragma unroll
      for (int j = 0; j < 4; j++) {
        int m = bm + wr * 64 + mi * 16 + fq * 4 + j;
        partial[((size_t)kc * 256 + m) * C_ + n] = acc[mi][ni][j];
      }
  }
}

// ---------------------------------------------------------------------------
__global__ __launch_bounds__(256) void k_splitk_reduce(const float* __restrict__ partial,
                                                       const float* __restrict__ bias,
                                                       float* __restrict__ outf) {
  int m = blockIdx.x;
  for (int n = threadIdx.x; n < C_; n += 256) {
    float s = 0.f;
    #pragma unroll
    for (int kc = 0; kc < SK; kc++)
      s += partial[((size_t)kc * 256 + m) * C_ + n];
    outf[(size_t)m * C_ + n] = s + bias[n];
  }
}

// ---------------------------------------------------------------------------
// Sparse gather attention, split across ASPLIT blocks per (q,h).
__global__ __launch_bounds__(256) void k_attn_split(const float* __restrict__ qb,
                                                    const unsigned short* __restrict__ kb,
                                                    const unsigned short* __restrict__ vb,
                                                    const int* __restrict__ cnt_g,
                                                    const int* __restrict__ idxg,
                                                    float* __restrict__ pmax,
                                                    float* __restrict__ psum,
                                                    float* __restrict__ pacc) {
  int q = blockIdx.x, h = blockIdx.y, sp = blockIdx.z;
  int tid = threadIdx.x;
  int lane = tid & 63, wid = tid >> 6;

  __shared__ float qs[64];
  __shared__ float sc[CAP / ASPLIT];   // 128
  __shared__ int   ls[CAP / ASPLIT];
  __shared__ float wred[4];
  __shared__ float accb[4][64];

  int cnt = cnt_g[q];
  int cq = (cnt + ASPLIT - 1) / ASPLIT;
  int beg = sp * cq;
  int end = beg + cq; if (end > cnt) end = cnt;
  int ns = end - beg; if (ns < 0) ns = 0;

  if (tid < 64) qs[tid] = qb[(size_t)q * C_ + h * HD_ + tid] * 0.125f;
  __syncthreads();

  if (tid < ns) {
    int l = idxg[(size_t)q * CAP + beg + tid];
    ls[tid] = l;
    const u16x8* kr = (const u16x8*)(kb + (size_t)l * C_ + h * HD_);
    float s = 0.f;
    #pragma unroll
    for (int v8 = 0; v8 < 8; v8++) {
      u16x8 kv = kr[v8];
      #pragma unroll
      for (int e = 0; e < 8; e++) s = fmaf(qs[v8 * 8 + e], bf2f(kv[e]), s);
    }
    sc[tid] = s;
  }
  __syncthreads();

  float lm = (tid < ns) ? sc[tid] : -INFINITY;
  #pragma unroll
  for (int off = 32; off; off >>= 1) lm = fmaxf(lm, __shfl_xor(lm, off));
  if (lane == 0) wred[wid] = lm;
  __syncthreads();
  float m4 = fmaxf(fmaxf(wred[0], wred[1]), fmaxf(wred[2], wred[3]));

  float e = 0.f;
  if (tid < ns) {
    e = expf(sc[tid] - m4);
    sc[tid] = e;
  }
  float lsum = e;
  #pragma unroll
  for (int off = 32; off; off >>= 1) lsum += __shfl_xor(lsum, off);
  __syncthreads();
  if (lane == 0) wred[wid] = lsum;
  __syncthreads();
  float S4 = wred[0] + wred[1] + wred[2] + wred[3];

  float acc = 0.f;
  for (int j = wid; j < ns; j += 4)
    acc = fmaf(sc[j], bf2f(vb[(size_t)ls[j] * C_ + h * HD_ + lane]), acc);
  accb[wid][lane] = acc;
  __syncthreads();

  int pidx = (q * NH_ + h) * ASPLIT + sp;
  if (tid < 64)
    pacc[(size_t)pidx * 64 + tid] =
        accb[0][tid] + accb[1][tid] + accb[2][tid] + accb[3][tid];
  if (tid == 0) {
    pmax[pidx] = (ns > 0) ? m4 : -INFINITY;
    psum[pidx] = S4;
  }
}

// ---------------------------------------------------------------------------
__global__ __launch_bounds__(64) void k_attn_merge(const float* __restrict__ pmax,
                                                   const float* __restrict__ psum,
                                                   const float* __restrict__ pacc,
                                                   unsigned short* __restrict__ ctxbf) {
  int q = blockIdx.x, h = blockIdx.y;
  int d = threadIdx.x;
  int base = (q * NH_ + h) * ASPLIT;
  float M = -INFINITY;
  #pragma unroll
  for (int s = 0; s < ASPLIT; s++) M = fmaxf(M, pmax[base + s]);
  float S = 0.f, a = 0.f;
  #pragma unroll
  for (int s = 0; s < ASPLIT; s++) {
    float wgt = expf(pmax[base + s] - M);
    S += psum[base + s] * wgt;
    a += pacc[(size_t)(base + s) * 64 + d] * wgt;
  }
  ctxbf[(size_t)q * C_ + h * HD_ + d] = f2bf(a / S);
}

// ---------------------------------------------------------------------------
extern "C" void kernel_launch(void* const* d_in, const int* in_sizes, int n_in,
                              void* d_out, int out_size, void* d_ws, size_t ws_size,
                              hipStream_t stream) {
  const float* x     = (const float*)d_in[0];
  const float* masks = (const float*)d_in[1];
  const float* Wq    = (const float*)d_in[2];
  const float* bq    = (const float*)d_in[3];
  const float* Wk    = (const float*)d_in[4];
  const float* bk    = (const float*)d_in[5];
  const float* Wv    = (const float*)d_in[6];
  const float* bv    = (const float*)d_in[7];
  const float* Wc    = (const float*)d_in[8];
  const float* bc    = (const float*)d_in[9];
  float* out = (float*)d_out;

  char* p = (char*)d_ws;
  auto alloc = [&](size_t bytes) {
    char* r = p;
    p += (bytes + 255) & ~(size_t)255;
    return r;
  };
  float* msig    = (float*)alloc((size_t)Q_ * HW_ * 4);
  float* w       = (float*)alloc(1024);
  float* qbuf    = (float*)alloc((size_t)Q_ * C_ * 4);
  float* partial = (float*)alloc((size_t)KSPLIT * 256 * C_ * 4);
  int*   cnt     = (int*)alloc(1024);
  int*   idxg    = (int*)alloc((size_t)Q_ * CAP * 4);
  float* pmax    = (float*)alloc((size_t)Q_ * NH_ * ASPLIT * 4);
  float* psum    = (float*)alloc((size_t)Q_ * NH_ * ASPLIT * 4);
  float* pacc    = (float*)alloc((size_t)Q_ * NH_ * ASPLIT * 64 * 4);
  unsigned short* msigbf = (unsigned short*)alloc((size_t)256 * HW_ * 2);
  unsigned short* xbf    = (unsigned short*)alloc((size_t)C_ * HW_ * 2);
  unsigned short* seqbf  = (unsigned short*)alloc((size_t)L_ * C_ * 2);
  unsigned short* wkbf   = (unsigned short*)alloc((size_t)C_ * C_ * 2);
  unsigned short* wvbf   = (unsigned short*)alloc((size_t)C_ * C_ * 2);
  unsigned short* wqbf   = (unsigned short*)alloc((size_t)C_ * C_ * 2);
  unsigned short* wcbf   = (unsigned short*)alloc((size_t)C_ * C_ * 2);
  unsigned short* ctxbf  = (unsigned short*)alloc((size_t)256 * C_ * 2);
  unsigned short* kbuf   = (unsigned short*)alloc((size_t)L_ * C_ * 2);
  unsigned short* vbuf   = (unsigned short*)alloc((size_t)L_ * C_ * 2);

  k_sigmoid_w<<<256, 256, 0, stream>>>(masks, msig, msigbf, w);
  k_compact<<<Q_, 256, 0, stream>>>(msig, cnt, idxg);
  k_xcast<<<dim3(HW_ / 32, C_ / 32), dim3(32, 8), 0, stream>>>(x, xbf, seqbf);
  k_cast<<<512, 256, 0, stream>>>(Wk, wkbf, C_ * C_);
  k_cast<<<512, 256, 0, stream>>>(Wv, wvbf, C_ * C_);
  k_cast<<<512, 256, 0, stream>>>(Wq, wqbf, C_ * C_);
  k_cast<<<512, 256, 0, stream>>>(Wc, wcbf, C_ * C_);
  // mean: split-K MFMA + reduce (writes seqbf rows 0..Q-1)
  k_gemm_meank<<<dim3(C_ / GBN, 2, KSPLIT), 256, 0, stream>>>(msigbf, xbf, partial);
  k_mean_reduce<<<Q_, 256, 0, stream>>>(partial, w, seqbf);
  // Q projection (bf16 split-K)
  k_gemm_splitk_bf<<<dim3(C_ / GBN, 2, SK), 256, 0, stream>>>(seqbf, wqbf, partial, Q_, C_);
  k_splitk_reduce<<<Q_, 256, 0, stream>>>(partial, bq, qbuf);
  // Fused K+V projections (bf16 MFMA, bf16 outputs), XCD-local tile order
  k_gemm_kv<<<8 * ((L_ + GBM - 1) / GBM), 512, 0, stream>>>(
      seqbf, wkbf, wvbf, bk, bv, kbuf, vbuf, L_, C_);
  // sparse attention (split + merge -> ctxbf)
  k_attn_split<<<dim3(Q_, NH_, ASPLIT), 256, 0, stream>>>(
      qbuf, kbuf, vbuf, cnt, idxg, pmax, psum, pacc);
  k_attn_merge<<<dim3(Q_, NH_), 64, 0, stream>>>(pmax, psum, pacc, ctxbf);
  // output projection (bf16 split-K)
  k_gemm_splitk_bf<<<dim3(C_ / GBN, 2, SK), 256, 0, stream>>>(ctxbf, wcbf, partial, Q_, C_);
  k_splitk_reduce<<<Q_, 256, 0, stream>>>(partial, bc, out);
}

// Round 8
// 359.492 us; speedup vs baseline: 11.7905x; 1.0062x over previous
//
#include <hip/hip_runtime.h>
#include <math.h>

#define HW_  16384
#define Q_   200
#define C_   1024
#define L_   16584   // Q_ + HW_
#define NH_  16
#define HD_  64
#define CAP  512
#define KSPLIT 8
#define KCH  (HW_ / KSPLIT)   // 2048
#define ASPLIT 4
#define SK   8                // split-K for small projections

typedef __attribute__((ext_vector_type(8))) __bf16 bf16x8;
typedef __attribute__((ext_vector_type(8))) unsigned short u16x8;
typedef __attribute__((ext_vector_type(4))) unsigned short u16x4;
typedef __attribute__((ext_vector_type(4))) float f32x4;

__device__ inline unsigned short f2bf(float f) {
  unsigned int u = __float_as_uint(f);
  u += 0x7fff + ((u >> 16) & 1);   // round-to-nearest-even
  return (unsigned short)(u >> 16);
}
__device__ inline float bf2f(unsigned short u) {
  return __uint_as_float((unsigned int)u << 16);
}

// ---------------------------------------------------------------------------
// sigmoid(masks) -> msig fp32 + msigbf bf16 (rows >= Q_ zeroed); w[q] = row sum
__global__ __launch_bounds__(256) void k_sigmoid_w(const float* __restrict__ masks,
                                                   float* __restrict__ msig,
                                                   unsigned short* __restrict__ msigbf,
                                                   float* __restrict__ w) {
  int q = blockIdx.x;
  int tid = threadIdx.x;
  unsigned short* obf = msigbf + (size_t)q * HW_;
  if (q >= Q_) {
    for (int i = tid; i < HW_; i += 256) obf[i] = 0;
    return;
  }
  const float* mrow = masks + (size_t)q * HW_;
  float* orow = msig + (size_t)q * HW_;
  float s = 0.f;
  for (int i = tid; i < HW_; i += 256) {
    float v = mrow[i];
    float sg = 1.f / (1.f + expf(-v));
    orow[i] = sg;
    obf[i] = f2bf(sg);
    s += sg;
  }
  __shared__ float red[256];
  red[tid] = s;
  __syncthreads();
  for (int off = 128; off > 0; off >>= 1) {
    if (tid < off) red[tid] += red[tid + off];
    __syncthreads();
  }
  if (tid == 0) w[q] = red[0];
}

// ---------------------------------------------------------------------------
// Deterministic per-query compaction of allowed pixel indices.
__global__ __launch_bounds__(256) void k_compact(const float* __restrict__ msig,
                                                 int* __restrict__ cnt,
                                                 int* __restrict__ idxg) {
  int q = blockIdx.x;
  int tid = threadIdx.x;
  const float* mrow = msig + (size_t)q * HW_;
  const int CHUNK = HW_ / 256;  // 64
  int base = tid * CHUNK;
  int my = 0;
  for (int j = 0; j < CHUNK; j++) my += (mrow[base + j] > 0.9f) ? 1 : 0;
  __shared__ int sc[256];
  sc[tid] = my;
  __syncthreads();
  for (int off = 1; off < 256; off <<= 1) {
    int v = sc[tid];
    int add = (tid >= off) ? sc[tid - off] : 0;
    __syncthreads();
    sc[tid] = v + add;
    __syncthreads();
  }
  int excl = sc[tid] - my;
  int total = sc[255];
  int* orow = idxg + (size_t)q * CAP;
  int off = 1 + excl;  // slot 0 = self
  for (int j = 0; j < CHUNK; j++) {
    if (mrow[base + j] > 0.9f) {
      if (off < CAP) orow[off] = Q_ + base + j;
      off++;
    }
  }
  if (tid == 0) {
    orow[0] = q;
    int c = 1 + total;
    cnt[q] = c < CAP ? c : CAP;
  }
}

// ---------------------------------------------------------------------------
// x [C][HW] fp32 -> xbf [C][HW] bf16 (same layout) + seqbf pixel rows (transposed)
__global__ __launch_bounds__(256) void k_xcast(const float* __restrict__ x,
                                               unsigned short* __restrict__ xbf,
                                               unsigned short* __restrict__ seqbf) {
  __shared__ float t[32][33];
  int l0 = blockIdx.x * 32, c0 = blockIdx.y * 32;
  int tx = threadIdx.x, ty = threadIdx.y;  // (32,8)
  #pragma unroll
  for (int i = 0; i < 32; i += 8) {
    float v = x[(size_t)(c0 + ty + i) * HW_ + l0 + tx];
    t[ty + i][tx] = v;
    xbf[(size_t)(c0 + ty + i) * HW_ + l0 + tx] = f2bf(v);
  }
  __syncthreads();
  #pragma unroll
  for (int i = 0; i < 32; i += 8)
    seqbf[(size_t)(Q_ + l0 + ty + i) * C_ + c0 + tx] = f2bf(t[tx][ty + i]);
}

// ---------------------------------------------------------------------------
__global__ __launch_bounds__(256) void k_cast(const float* __restrict__ in,
                                              unsigned short* __restrict__ out, int n) {
  int stride = gridDim.x * 256;
  for (int i = blockIdx.x * 256 + threadIdx.x; i < n; i += stride)
    out[i] = f2bf(in[i]);
}

#define GBM 128
#define GBN 128
#define GBK 32

// ---------------------------------------------------------------------------
// Fused K+V projection GEMM. 512 threads = 8 waves.
// Waves 0-3: K-output 128x128 tile (2x2 wave grid); waves 4-7: V-output.
// A-tile (seqbf) staged ONCE per K-step for both outputs.
// MFMA operands SWAPPED so lane acc runs along N -> vectorized 8B stores.
__global__ __launch_bounds__(512) void k_gemm_kv(const unsigned short* __restrict__ A,
                                                 const unsigned short* __restrict__ Bk,
                                                 const unsigned short* __restrict__ Bv,
                                                 const float* __restrict__ bk,
                                                 const float* __restrict__ bv,
                                                 unsigned short* __restrict__ Ko,
                                                 unsigned short* __restrict__ Vo,
                                                 int M, int K) {
  __shared__ __attribute__((aligned(16))) unsigned short smem[3 * GBM * GBK]; // A | Bk | Bv
  int w = blockIdx.x;
  int nbm = gridDim.x >> 3;                  // 130
  int t = (w >> 3) + (w & 7) * nbm;          // contiguous t per XCD
  int bm = (t >> 3) * GBM;
  int bn = (t & 7) * GBN;
  int tid = threadIdx.x;
  int wid = tid >> 6, lane = tid & 63;
  int w2 = wid & 3;
  int wr = w2 >> 1, wc = w2 & 1;
  int fq = lane >> 4, fr = lane & 15;
  int srow = lane >> 2;
  int scol = (lane & 3) * 8;
  const unsigned short (*As)[GBK]  = (const unsigned short (*)[GBK])(smem);
  const unsigned short (*Bts)[GBK] = (const unsigned short (*)[GBK])(smem + (wid < 4 ? GBM * GBK : 2 * GBM * GBK));
  f32x4 acc[4][4] = {};
  for (int k0 = 0; k0 < K; k0 += GBK) {
    __syncthreads();
    #pragma unroll
    for (int i = 0; i < 3; i++) {
      int ci = wid * 3 + i;                  // 0..23 chunk of 1 KB
      const unsigned short* src;
      if (ci < 8) {
        int gA = bm + ci * 16 + srow; if (gA > M - 1) gA = M - 1;
        src = A + (size_t)gA * K + k0 + scol;
      } else if (ci < 16) {
        src = Bk + (size_t)(bn + (ci - 8) * 16 + srow) * K + k0 + scol;
      } else {
        src = Bv + (size_t)(bn + (ci - 16) * 16 + srow) * K + k0 + scol;
      }
      __builtin_amdgcn_global_load_lds(
          (const __attribute__((address_space(1))) void*)src,
          (__attribute__((address_space(3))) void*)((char*)smem + ci * 1024),
          16, 0, 0);
    }
    __syncthreads();
    bf16x8 af[4], bfr[4];
    #pragma unroll
    for (int mi = 0; mi < 4; mi++)
      af[mi] = *(const bf16x8*)&As[wr * 64 + mi * 16 + fr][fq * 8];
    #pragma unroll
    for (int ni = 0; ni < 4; ni++)
      bfr[ni] = *(const bf16x8*)&Bts[wc * 64 + ni * 16 + fr][fq * 8];
    #pragma unroll
    for (int mi = 0; mi < 4; mi++)
      #pragma unroll
      for (int ni = 0; ni < 4; ni++)
        acc[mi][ni] = __builtin_amdgcn_mfma_f32_16x16x32_bf16(bfr[ni], af[mi], acc[mi][ni], 0, 0, 0);
  }
  // Swapped layout: lane value j -> n = bn + wc*64 + ni*16 + fq*4 + j,
  //                 m = bm + wr*64 + mi*16 + fr.
  const float* bias = (wid < 4) ? bk : bv;
  unsigned short* Cout = (wid < 4) ? Ko : Vo;
  #pragma unroll
  for (int ni = 0; ni < 4; ni++) {
    int n0 = bn + wc * 64 + ni * 16 + fq * 4;
    float4 b4 = *(const float4*)&bias[n0];
    float bb[4] = {b4.x, b4.y, b4.z, b4.w};
    #pragma unroll
    for (int mi = 0; mi < 4; mi++) {
      int m = bm + wr * 64 + mi * 16 + fr;
      if (m < M) {
        u16x4 o;
        #pragma unroll
        for (int j = 0; j < 4; j++) o[j] = f2bf(acc[mi][ni][j] + bb[j]);
        *(u16x4*)&Cout[(size_t)m * C_ + n0] = o;
      }
    }
  }
}

// ---------------------------------------------------------------------------
// Split-K mean GEMM: A = msigbf [256][HW_], B = xbf [1024][HW_]; z = K-chunk.
// Swapped operands -> f32x4 stores.
__global__ __launch_bounds__(256) void k_gemm_meank(const unsigned short* __restrict__ A,
                                                    const unsigned short* __restrict__ B,
                                                    float* __restrict__ partial) {
  __shared__ __attribute__((aligned(16))) unsigned short As[GBM][GBK];
  __shared__ __attribute__((aligned(16))) unsigned short Bs[GBN][GBK];
  int bm = blockIdx.y * GBM, bn = blockIdx.x * GBN;
  int kc = blockIdx.z;
  int tid = threadIdx.x;
  int wid = tid >> 6, lane = tid & 63;
  int wr = wid >> 1, wc = wid & 1;
  int fq = lane >> 4, fr = lane & 15;
  int srow = lane >> 2;
  int scol = (lane & 3) * 8;
  f32x4 acc[4][4] = {};
  int kbeg = kc * KCH, kend = kbeg + KCH;
  for (int k0 = kbeg; k0 < kend; k0 += GBK) {
    __syncthreads();
    #pragma unroll
    for (int i = 0; i < 2; i++) {
      int r = wid * 32 + i * 16 + srow;
      __builtin_amdgcn_global_load_lds(
          (const __attribute__((address_space(1))) void*)(A + (size_t)(bm + r) * HW_ + k0 + scol),
          (__attribute__((address_space(3))) void*)((char*)&As[0][0] + (wid * 2 + i) * 1024),
          16, 0, 0);
      __builtin_amdgcn_global_load_lds(
          (const __attribute__((address_space(1))) void*)(B + (size_t)(bn + r) * HW_ + k0 + scol),
          (__attribute__((address_space(3))) void*)((char*)&Bs[0][0] + (wid * 2 + i) * 1024),
          16, 0, 0);
    }
    __syncthreads();
    bf16x8 af[4], bfr[4];
    #pragma unroll
    for (int mi = 0; mi < 4; mi++)
      af[mi] = *(const bf16x8*)&As[wr * 64 + mi * 16 + fr][fq * 8];
    #pragma unroll
    for (int ni = 0; ni < 4; ni++)
      bfr[ni] = *(const bf16x8*)&Bs[wc * 64 + ni * 16 + fr][fq * 8];
    #pragma unroll
    for (int mi = 0; mi < 4; mi++)
      #pragma unroll
      for (int ni = 0; ni < 4; ni++)
        acc[mi][ni] = __builtin_amdgcn_mfma_f32_16x16x32_bf16(bfr[ni], af[mi], acc[mi][ni], 0, 0, 0);
  }
  #pragma unroll
  for (int ni = 0; ni < 4; ni++) {
    int n0 = bn + wc * 64 + ni * 16 + fq * 4;
    #pragma unroll
    for (int mi = 0; mi < 4; mi++) {
      int m = bm + wr * 64 + mi * 16 + fr;
      *(f32x4*)&partial[((size_t)kc * 256 + m) * C_ + n0] = acc[mi][ni];
    }
  }
}

// ---------------------------------------------------------------------------
// mean = (sum of partials) / (w + 1e-3) -> seqbf rows 0..Q-1 (bf16)
__global__ __launch_bounds__(256) void k_mean_reduce(const float* __restrict__ partial,
                                                     const float* __restrict__ w,
                                                     unsigned short* __restrict__ seqbf) {
  int m = blockIdx.x;  // 0..Q_-1
  float rs = 1.f / (w[m] + 0.001f);
  for (int n = threadIdx.x; n < C_; n += 256) {
    float s = 0.f;
    #pragma unroll
    for (int kc = 0; kc < KSPLIT; kc++)
      s += partial[((size_t)kc * 256 + m) * C_ + n];
    seqbf[(size_t)m * C_ + n] = f2bf(s * rs);
  }
}

// ---------------------------------------------------------------------------
// Split-K bf16 MFMA GEMM for small-M projections. K=1024, SK chunks.
// Swapped operands -> f32x4 stores.
__global__ __launch_bounds__(256) void k_gemm_splitk_bf(const unsigned short* __restrict__ A,
                                                        const unsigned short* __restrict__ B,
                                                        float* __restrict__ partial,
                                                        int M, int K) {
  __shared__ __attribute__((aligned(16))) unsigned short As[GBM][GBK];
  __shared__ __attribute__((aligned(16))) unsigned short Bs[GBN][GBK];
  int bm = blockIdx.y * GBM, bn = blockIdx.x * GBN;
  int kc = blockIdx.z;
  int kchunk = K / SK;
  int tid = threadIdx.x;
  int wid = tid >> 6, lane = tid & 63;
  int wr = wid >> 1, wc = wid & 1;
  int fq = lane >> 4, fr = lane & 15;
  int srow = lane >> 2;
  int scol = (lane & 3) * 8;
  f32x4 acc[4][4] = {};
  int kbeg = kc * kchunk, kend = kbeg + kchunk;
  for (int k0 = kbeg; k0 < kend; k0 += GBK) {
    __syncthreads();
    #pragma unroll
    for (int i = 0; i < 2; i++) {
      int r = wid * 32 + i * 16 + srow;
      int gA = bm + r; if (gA > M - 1) gA = M - 1;
      __builtin_amdgcn_global_load_lds(
          (const __attribute__((address_space(1))) void*)(A + (size_t)gA * K + k0 + scol),
          (__attribute__((address_space(3))) void*)((char*)&As[0][0] + (wid * 2 + i) * 1024),
          16, 0, 0);
      __builtin_amdgcn_global_load_lds(
          (const __attribute__((address_space(1))) void*)(B + (size_t)(bn + r) * K + k0 + scol),
          (__attribute__((address_space(3))) void*)((char*)&Bs[0][0] + (wid * 2 + i) * 1024),
          16, 0, 0);
    }
    __syncthreads();
    bf16x8 af[4], bfr[4];
    #pragma unroll
    for (int mi = 0; mi < 4; mi++)
      af[mi] = *(const bf16x8*)&As[wr * 64 + mi * 16 + fr][fq * 8];
    #pragma unroll
    for (int ni = 0; ni < 4; ni++)
      bfr[ni] = *(const bf16x8*)&Bs[wc * 64 + ni * 16 + fr][fq * 8];
    #pragma unroll
    for (int mi = 0; mi < 4; mi++)
      #pragma unroll
      for (int ni = 0; ni < 4; ni++)
        acc[mi][ni] = __builtin_amdgcn_mfma_f32_16x16x32_bf16(bfr[ni], af[mi], acc[mi][ni], 0, 0, 0);
  }
  #pragma unroll
  for (int ni = 0; ni < 4; ni++) {
    int n0 = bn + wc * 64 + ni * 16 + fq * 4;
    #pragma unroll
    for (int mi = 0; mi < 4; mi++) {
      int m = bm + wr * 64 + mi * 16 + fr;
      *(f32x4*)&partial[((size_t)kc * 256 + m) * C_ + n0] = acc[mi][ni];
    }
  }
}

// ---------------------------------------------------------------------------
__global__ __launch_bounds__(256) void k_splitk_reduce(const float* __restrict__ partial,
                                                       const float* __restrict__ bias,
                                                       float* __restrict__ outf) {
  int m = blockIdx.x;
  for (int n = threadIdx.x; n < C_; n += 256) {
    float s = 0.f;
    #pragma unroll
    for (int kc = 0; kc < SK; kc++)
      s += partial[((size_t)kc * 256 + m) * C_ + n];
    outf[(size_t)m * C_ + n] = s + bias[n];
  }
}

// ---------------------------------------------------------------------------
// Sparse gather attention, split across ASPLIT blocks per (q,h).
__global__ __launch_bounds__(256) void k_attn_split(const float* __restrict__ qb,
                                                    const unsigned short* __restrict__ kb,
                                                    const unsigned short* __restrict__ vb,
                                                    const int* __restrict__ cnt_g,
                                                    const int* __restrict__ idxg,
                                                    float* __restrict__ pmax,
                                                    float* __restrict__ psum,
                                                    float* __restrict__ pacc) {
  int q = blockIdx.x, h = blockIdx.y, sp = blockIdx.z;
  int tid = threadIdx.x;
  int lane = tid & 63, wid = tid >> 6;

  __shared__ float qs[64];
  __shared__ float sc[CAP / ASPLIT];   // 128
  __shared__ int   ls[CAP / ASPLIT];
  __shared__ float wred[4];
  __shared__ float accb[4][64];

  int cnt = cnt_g[q];
  int cq = (cnt + ASPLIT - 1) / ASPLIT;
  int beg = sp * cq;
  int end = beg + cq; if (end > cnt) end = cnt;
  int ns = end - beg; if (ns < 0) ns = 0;

  if (tid < 64) qs[tid] = qb[(size_t)q * C_ + h * HD_ + tid] * 0.125f;
  __syncthreads();

  if (tid < ns) {
    int l = idxg[(size_t)q * CAP + beg + tid];
    ls[tid] = l;
    const u16x8* kr = (const u16x8*)(kb + (size_t)l * C_ + h * HD_);
    float s = 0.f;
    #pragma unroll
    for (int v8 = 0; v8 < 8; v8++) {
      u16x8 kv = kr[v8];
      #pragma unroll
      for (int e = 0; e < 8; e++) s = fmaf(qs[v8 * 8 + e], bf2f(kv[e]), s);
    }
    sc[tid] = s;
  }
  __syncthreads();

  float lm = (tid < ns) ? sc[tid] : -INFINITY;
  #pragma unroll
  for (int off = 32; off; off >>= 1) lm = fmaxf(lm, __shfl_xor(lm, off));
  if (lane == 0) wred[wid] = lm;
  __syncthreads();
  float m4 = fmaxf(fmaxf(wred[0], wred[1]), fmaxf(wred[2], wred[3]));

  float e = 0.f;
  if (tid < ns) {
    e = expf(sc[tid] - m4);
    sc[tid] = e;
  }
  float lsum = e;
  #pragma unroll
  for (int off = 32; off; off >>= 1) lsum += __shfl_xor(lsum, off);
  __syncthreads();
  if (lane == 0) wred[wid] = lsum;
  __syncthreads();
  float S4 = wred[0] + wred[1] + wred[2] + wred[3];

  float acc = 0.f;
  for (int j = wid; j < ns; j += 4)
    acc = fmaf(sc[j], bf2f(vb[(size_t)ls[j] * C_ + h * HD_ + lane]), acc);
  accb[wid][lane] = acc;
  __syncthreads();

  int pidx = (q * NH_ + h) * ASPLIT + sp;
  if (tid < 64)
    pacc[(size_t)pidx * 64 + tid] =
        accb[0][tid] + accb[1][tid] + accb[2][tid] + accb[3][tid];
  if (tid == 0) {
    pmax[pidx] = (ns > 0) ? m4 : -INFINITY;
    psum[pidx] = S4;
  }
}

// ---------------------------------------------------------------------------
__global__ __launch_bounds__(64) void k_attn_merge(const float* __restrict__ pmax,
                                                   const float* __restrict__ psum,
                                                   const float* __restrict__ pacc,
                                                   unsigned short* __restrict__ ctxbf) {
  int q = blockIdx.x, h = blockIdx.y;
  int d = threadIdx.x;
  int base = (q * NH_ + h) * ASPLIT;
  float M = -INFINITY;
  #pragma unroll
  for (int s = 0; s < ASPLIT; s++) M = fmaxf(M, pmax[base + s]);
  float S = 0.f, a = 0.f;
  #pragma unroll
  for (int s = 0; s < ASPLIT; s++) {
    float wgt = expf(pmax[base + s] - M);
    S += psum[base + s] * wgt;
    a += pacc[(size_t)(base + s) * 64 + d] * wgt;
  }
  ctxbf[(size_t)q * C_ + h * HD_ + d] = f2bf(a / S);
}

// ---------------------------------------------------------------------------
extern "C" void kernel_launch(void* const* d_in, const int* in_sizes, int n_in,
                              void* d_out, int out_size, void* d_ws, size_t ws_size,
                              hipStream_t stream) {
  const float* x     = (const float*)d_in[0];
  const float* masks = (const float*)d_in[1];
  const float* Wq    = (const float*)d_in[2];
  const float* bq    = (const float*)d_in[3];
  const float* Wk    = (const float*)d_in[4];
  const float* bk    = (const float*)d_in[5];
  const float* Wv    = (const float*)d_in[6];
  const float* bv    = (const float*)d_in[7];
  const float* Wc    = (const float*)d_in[8];
  const float* bc    = (const float*)d_in[9];
  float* out = (float*)d_out;

  char* p = (char*)d_ws;
  auto alloc = [&](size_t bytes) {
    char* r = p;
    p += (bytes + 255) & ~(size_t)255;
    return r;
  };
  float* msig    = (float*)alloc((size_t)Q_ * HW_ * 4);
  float* w       = (float*)alloc(1024);
  float* qbuf    = (float*)alloc((size_t)Q_ * C_ * 4);
  float* partial = (float*)alloc((size_t)KSPLIT * 256 * C_ * 4);
  int*   cnt     = (int*)alloc(1024);
  int*   idxg    = (int*)alloc((size_t)Q_ * CAP * 4);
  float* pmax    = (float*)alloc((size_t)Q_ * NH_ * ASPLIT * 4);
  float* psum    = (float*)alloc((size_t)Q_ * NH_ * ASPLIT * 4);
  float* pacc    = (float*)alloc((size_t)Q_ * NH_ * ASPLIT * 64 * 4);
  unsigned short* msigbf = (unsigned short*)alloc((size_t)256 * HW_ * 2);
  unsigned short* xbf    = (unsigned short*)alloc((size_t)C_ * HW_ * 2);
  unsigned short* seqbf  = (unsigned short*)alloc((size_t)L_ * C_ * 2);
  unsigned short* wkbf   = (unsigned short*)alloc((size_t)C_ * C_ * 2);
  unsigned short* wvbf   = (unsigned short*)alloc((size_t)C_ * C_ * 2);
  unsigned short* wqbf   = (unsigned short*)alloc((size_t)C_ * C_ * 2);
  unsigned short* wcbf   = (unsigned short*)alloc((size_t)C_ * C_ * 2);
  unsigned short* ctxbf  = (unsigned short*)alloc((size_t)256 * C_ * 2);
  unsigned short* kbuf   = (unsigned short*)alloc((size_t)L_ * C_ * 2);
  unsigned short* vbuf   = (unsigned short*)alloc((size_t)L_ * C_ * 2);

  k_sigmoid_w<<<256, 256, 0, stream>>>(masks, msig, msigbf, w);
  k_compact<<<Q_, 256, 0, stream>>>(msig, cnt, idxg);
  k_xcast<<<dim3(HW_ / 32, C_ / 32), dim3(32, 8), 0, stream>>>(x, xbf, seqbf);
  k_cast<<<512, 256, 0, stream>>>(Wk, wkbf, C_ * C_);
  k_cast<<<512, 256, 0, stream>>>(Wv, wvbf, C_ * C_);
  k_cast<<<512, 256, 0, stream>>>(Wq, wqbf, C_ * C_);
  k_cast<<<512, 256, 0, stream>>>(Wc, wcbf, C_ * C_);
  // mean: split-K MFMA + reduce (writes seqbf rows 0..Q-1)
  k_gemm_meank<<<dim3(C_ / GBN, 2, KSPLIT), 256, 0, stream>>>(msigbf, xbf, partial);
  k_mean_reduce<<<Q_, 256, 0, stream>>>(partial, w, seqbf);
  // Q projection (bf16 split-K)
  k_gemm_splitk_bf<<<dim3(C_ / GBN, 2, SK), 256, 0, stream>>>(seqbf, wqbf, partial, Q_, C_);
  k_splitk_reduce<<<Q_, 256, 0, stream>>>(partial, bq, qbuf);
  // Fused K+V projections (bf16 MFMA, bf16 outputs), XCD-local tile order
  k_gemm_kv<<<8 * ((L_ + GBM - 1) / GBM), 512, 0, stream>>>(
      seqbf, wkbf, wvbf, bk, bv, kbuf, vbuf, L_, C_);
  // sparse attention (split + merge -> ctxbf)
  k_attn_split<<<dim3(Q_, NH_, ASPLIT), 256, 0, stream>>>(
      qbuf, kbuf, vbuf, cnt, idxg, pmax, psum, pacc);
  k_attn_merge<<<dim3(Q_, NH_), 64, 0, stream>>>(pmax, psum, pacc, ctxbf);
  // output projection (bf16 split-K)
  k_gemm_splitk_bf<<<dim3(C_ / GBN, 2, SK), 256, 0, stream>>>(ctxbf, wcbf, partial, Q_, C_);
  k_splitk_reduce<<<Q_, 256, 0, stream>>>(partial, bc, out);
}

// Round 9
// 311.867 us; speedup vs baseline: 13.5910x; 1.1527x over previous
//
#include <hip/hip_runtime.h>
#include <math.h>

#define HW_  16384
#define Q_   200
#define C_   1024
#define L_   16584   // Q_ + HW_
#define NH_  16
#define HD_  64
#define CAP  512
#define KSPLIT 8
#define KCH  (HW_ / KSPLIT)   // 2048
#define ASPLIT 4
#define SK   8                // split-K for small projections

typedef __attribute__((ext_vector_type(8))) __bf16 bf16x8;
typedef __attribute__((ext_vector_type(8))) unsigned short u16x8;
typedef __attribute__((ext_vector_type(4))) unsigned short u16x4;
typedef __attribute__((ext_vector_type(4))) float f32x4;

__device__ inline unsigned short f2bf(float f) {
  unsigned int u = __float_as_uint(f);
  u += 0x7fff + ((u >> 16) & 1);   // round-to-nearest-even
  return (unsigned short)(u >> 16);
}
__device__ inline float bf2f(unsigned short u) {
  return __uint_as_float((unsigned int)u << 16);
}

// ---------------------------------------------------------------------------
// sigmoid(masks) -> msig fp32 + msigbf bf16 (rows >= Q_ zeroed); w[q] = row sum
__global__ __launch_bounds__(256) void k_sigmoid_w(const float* __restrict__ masks,
                                                   float* __restrict__ msig,
                                                   unsigned short* __restrict__ msigbf,
                                                   float* __restrict__ w) {
  int q = blockIdx.x;
  int tid = threadIdx.x;
  unsigned short* obf = msigbf + (size_t)q * HW_;
  if (q >= Q_) {
    u16x4 z = {0, 0, 0, 0};
    for (int i = tid; i < HW_ / 4; i += 256) *(u16x4*)&obf[i * 4] = z;
    return;
  }
  const float4* mrow4 = (const float4*)(masks + (size_t)q * HW_);
  float4* orow4 = (float4*)(msig + (size_t)q * HW_);
  float s = 0.f;
  for (int i = tid; i < HW_ / 4; i += 256) {
    float4 v = mrow4[i];
    float4 sg;
    sg.x = 1.f / (1.f + expf(-v.x));
    sg.y = 1.f / (1.f + expf(-v.y));
    sg.z = 1.f / (1.f + expf(-v.z));
    sg.w = 1.f / (1.f + expf(-v.w));
    orow4[i] = sg;
    u16x4 o = {f2bf(sg.x), f2bf(sg.y), f2bf(sg.z), f2bf(sg.w)};
    *(u16x4*)&obf[i * 4] = o;
    s += sg.x + sg.y + sg.z + sg.w;
  }
  __shared__ float red[256];
  red[tid] = s;
  __syncthreads();
  for (int off = 128; off > 0; off >>= 1) {
    if (tid < off) red[tid] += red[tid + off];
    __syncthreads();
  }
  if (tid == 0) w[q] = red[0];
}

// ---------------------------------------------------------------------------
// Deterministic per-query compaction of allowed pixel indices.
__global__ __launch_bounds__(256) void k_compact(const float* __restrict__ msig,
                                                 int* __restrict__ cnt,
                                                 int* __restrict__ idxg) {
  int q = blockIdx.x;
  int tid = threadIdx.x;
  const float* mrow = msig + (size_t)q * HW_;
  const int CHUNK = HW_ / 256;  // 64
  int base = tid * CHUNK;
  int my = 0;
  for (int j = 0; j < CHUNK; j++) my += (mrow[base + j] > 0.9f) ? 1 : 0;
  __shared__ int sc[256];
  sc[tid] = my;
  __syncthreads();
  for (int off = 1; off < 256; off <<= 1) {
    int v = sc[tid];
    int add = (tid >= off) ? sc[tid - off] : 0;
    __syncthreads();
    sc[tid] = v + add;
    __syncthreads();
  }
  int excl = sc[tid] - my;
  int total = sc[255];
  int* orow = idxg + (size_t)q * CAP;
  int off = 1 + excl;  // slot 0 = self
  for (int j = 0; j < CHUNK; j++) {
    if (mrow[base + j] > 0.9f) {
      if (off < CAP) orow[off] = Q_ + base + j;
      off++;
    }
  }
  if (tid == 0) {
    orow[0] = q;
    int c = 1 + total;
    cnt[q] = c < CAP ? c : CAP;
  }
}

// ---------------------------------------------------------------------------
// x [C][HW] fp32 -> xbf [C][HW] bf16 (same layout) + seqbf pixel rows (transposed)
__global__ __launch_bounds__(256) void k_xcast(const float* __restrict__ x,
                                               unsigned short* __restrict__ xbf,
                                               unsigned short* __restrict__ seqbf) {
  __shared__ float t[32][33];
  int l0 = blockIdx.x * 32, c0 = blockIdx.y * 32;
  int tx = threadIdx.x, ty = threadIdx.y;  // (32,8)
  #pragma unroll
  for (int i = 0; i < 32; i += 8) {
    float v = x[(size_t)(c0 + ty + i) * HW_ + l0 + tx];
    t[ty + i][tx] = v;
    xbf[(size_t)(c0 + ty + i) * HW_ + l0 + tx] = f2bf(v);
  }
  __syncthreads();
  #pragma unroll
  for (int i = 0; i < 32; i += 8)
    seqbf[(size_t)(Q_ + l0 + ty + i) * C_ + c0 + tx] = f2bf(t[tx][ty + i]);
}

// ---------------------------------------------------------------------------
// Four weight casts in one launch. blockIdx.y selects tensor.
__global__ __launch_bounds__(256) void k_cast4(const float* __restrict__ s0,
                                               const float* __restrict__ s1,
                                               const float* __restrict__ s2,
                                               const float* __restrict__ s3,
                                               unsigned short* __restrict__ d0,
                                               unsigned short* __restrict__ d1,
                                               unsigned short* __restrict__ d2,
                                               unsigned short* __restrict__ d3) {
  const float* src = (blockIdx.y == 0) ? s0 : (blockIdx.y == 1) ? s1
                     : (blockIdx.y == 2) ? s2 : s3;
  unsigned short* dst = (blockIdx.y == 0) ? d0 : (blockIdx.y == 1) ? d1
                        : (blockIdx.y == 2) ? d2 : d3;
  int i = (blockIdx.x * 256 + threadIdx.x) * 4;
  float4 v = *(const float4*)&src[i];
  u16x4 o = {f2bf(v.x), f2bf(v.y), f2bf(v.z), f2bf(v.w)};
  *(u16x4*)&dst[i] = o;
}

#define GBM 128
#define GBN 128
#define GBK 32

// ---------------------------------------------------------------------------
// Fused K+V projection GEMM, double-buffered 2-phase pipeline.
// 512 threads = 8 waves; waves 0-3: K-output tile, waves 4-7: V-output tile.
// A-tile staged once per K-step for both outputs. One barrier per K-step:
// stage(next) -> ds_read+MFMA(cur) -> __syncthreads (drains vmcnt after the
// compute phase has covered most of the load latency).
__global__ __launch_bounds__(512) void k_gemm_kv(const unsigned short* __restrict__ A,
                                                 const unsigned short* __restrict__ Bk,
                                                 const unsigned short* __restrict__ Bv,
                                                 const float* __restrict__ bk,
                                                 const float* __restrict__ bv,
                                                 unsigned short* __restrict__ Ko,
                                                 unsigned short* __restrict__ Vo,
                                                 int M, int K) {
  __shared__ __attribute__((aligned(16))) unsigned short smem[2][3 * GBM * GBK]; // 48 KB
  int w = blockIdx.x;
  int nbm = gridDim.x >> 3;                  // 130
  int t = (w >> 3) + (w & 7) * nbm;          // contiguous t per XCD
  int bm = (t >> 3) * GBM;
  int bn = (t & 7) * GBN;
  int tid = threadIdx.x;
  int wid = tid >> 6, lane = tid & 63;
  int w2 = wid & 3;
  int wr = w2 >> 1, wc = w2 & 1;
  int fq = lane >> 4, fr = lane & 15;
  int srow = lane >> 2;
  int scol = (lane & 3) * 8;
  int boff = (wid < 4) ? GBM * GBK : 2 * GBM * GBK;

  auto stage = [&](int buf, int k0) {
    #pragma unroll
    for (int i = 0; i < 3; i++) {
      int ci = wid * 3 + i;                  // 0..23 chunks of 1 KB
      const unsigned short* src;
      if (ci < 8) {
        int gA = bm + ci * 16 + srow; if (gA > M - 1) gA = M - 1;
        src = A + (size_t)gA * K + k0 + scol;
      } else if (ci < 16) {
        src = Bk + (size_t)(bn + (ci - 8) * 16 + srow) * K + k0 + scol;
      } else {
        src = Bv + (size_t)(bn + (ci - 16) * 16 + srow) * K + k0 + scol;
      }
      __builtin_amdgcn_global_load_lds(
          (const __attribute__((address_space(1))) void*)src,
          (__attribute__((address_space(3))) void*)((char*)&smem[buf][0] + ci * 1024),
          16, 0, 0);
    }
  };

  f32x4 acc[4][4] = {};
  const int NT = K / GBK;
  stage(0, 0);
  __syncthreads();
  int cur = 0;
  for (int it = 0; it < NT; it++) {
    if (it + 1 < NT) stage(cur ^ 1, (it + 1) * GBK);
    const unsigned short (*As)[GBK]  = (const unsigned short (*)[GBK])(&smem[cur][0]);
    const unsigned short (*Bts)[GBK] = (const unsigned short (*)[GBK])(&smem[cur][0] + boff);
    bf16x8 af[4], bfr[4];
    #pragma unroll
    for (int mi = 0; mi < 4; mi++)
      af[mi] = *(const bf16x8*)&As[wr * 64 + mi * 16 + fr][fq * 8];
    #pragma unroll
    for (int ni = 0; ni < 4; ni++)
      bfr[ni] = *(const bf16x8*)&Bts[wc * 64 + ni * 16 + fr][fq * 8];
    #pragma unroll
    for (int mi = 0; mi < 4; mi++)
      #pragma unroll
      for (int ni = 0; ni < 4; ni++)
        acc[mi][ni] = __builtin_amdgcn_mfma_f32_16x16x32_bf16(bfr[ni], af[mi], acc[mi][ni], 0, 0, 0);
    __syncthreads();
    cur ^= 1;
  }
  // Swapped layout: lane value j -> n = bn + wc*64 + ni*16 + fq*4 + j,
  //                 m = bm + wr*64 + mi*16 + fr.
  const float* bias = (wid < 4) ? bk : bv;
  unsigned short* Cout = (wid < 4) ? Ko : Vo;
  #pragma unroll
  for (int ni = 0; ni < 4; ni++) {
    int n0 = bn + wc * 64 + ni * 16 + fq * 4;
    float4 b4 = *(const float4*)&bias[n0];
    float bb[4] = {b4.x, b4.y, b4.z, b4.w};
    #pragma unroll
    for (int mi = 0; mi < 4; mi++) {
      int m = bm + wr * 64 + mi * 16 + fr;
      if (m < M) {
        u16x4 o;
        #pragma unroll
        for (int j = 0; j < 4; j++) o[j] = f2bf(acc[mi][ni][j] + bb[j]);
        *(u16x4*)&Cout[(size_t)m * C_ + n0] = o;
      }
    }
  }
}

// ---------------------------------------------------------------------------
// Split-K mean GEMM, 2-phase: A = msigbf [256][HW_], B = xbf [1024][HW_].
__global__ __launch_bounds__(256) void k_gemm_meank(const unsigned short* __restrict__ A,
                                                    const unsigned short* __restrict__ B,
                                                    float* __restrict__ partial) {
  __shared__ __attribute__((aligned(16))) unsigned short As[2][GBM][GBK];
  __shared__ __attribute__((aligned(16))) unsigned short Bs[2][GBN][GBK];
  int bm = blockIdx.y * GBM, bn = blockIdx.x * GBN;
  int kc = blockIdx.z;
  int tid = threadIdx.x;
  int wid = tid >> 6, lane = tid & 63;
  int wr = wid >> 1, wc = wid & 1;
  int fq = lane >> 4, fr = lane & 15;
  int srow = lane >> 2;
  int scol = (lane & 3) * 8;

  auto stage = [&](int buf, int k0) {
    #pragma unroll
    for (int i = 0; i < 2; i++) {
      int r = wid * 32 + i * 16 + srow;
      __builtin_amdgcn_global_load_lds(
          (const __attribute__((address_space(1))) void*)(A + (size_t)(bm + r) * HW_ + k0 + scol),
          (__attribute__((address_space(3))) void*)((char*)&As[buf][0][0] + (wid * 2 + i) * 1024),
          16, 0, 0);
      __builtin_amdgcn_global_load_lds(
          (const __attribute__((address_space(1))) void*)(B + (size_t)(bn + r) * HW_ + k0 + scol),
          (__attribute__((address_space(3))) void*)((char*)&Bs[buf][0][0] + (wid * 2 + i) * 1024),
          16, 0, 0);
    }
  };

  f32x4 acc[4][4] = {};
  int kbeg = kc * KCH;
  const int NT = KCH / GBK;
  stage(0, kbeg);
  __syncthreads();
  int cur = 0;
  for (int it = 0; it < NT; it++) {
    if (it + 1 < NT) stage(cur ^ 1, kbeg + (it + 1) * GBK);
    bf16x8 af[4], bfr[4];
    #pragma unroll
    for (int mi = 0; mi < 4; mi++)
      af[mi] = *(const bf16x8*)&As[cur][wr * 64 + mi * 16 + fr][fq * 8];
    #pragma unroll
    for (int ni = 0; ni < 4; ni++)
      bfr[ni] = *(const bf16x8*)&Bs[cur][wc * 64 + ni * 16 + fr][fq * 8];
    #pragma unroll
    for (int mi = 0; mi < 4; mi++)
      #pragma unroll
      for (int ni = 0; ni < 4; ni++)
        acc[mi][ni] = __builtin_amdgcn_mfma_f32_16x16x32_bf16(bfr[ni], af[mi], acc[mi][ni], 0, 0, 0);
    __syncthreads();
    cur ^= 1;
  }
  #pragma unroll
  for (int ni = 0; ni < 4; ni++) {
    int n0 = bn + wc * 64 + ni * 16 + fq * 4;
    #pragma unroll
    for (int mi = 0; mi < 4; mi++) {
      int m = bm + wr * 64 + mi * 16 + fr;
      *(f32x4*)&partial[((size_t)kc * 256 + m) * C_ + n0] = acc[mi][ni];
    }
  }
}

// ---------------------------------------------------------------------------
// mean = (sum of partials) / (w + 1e-3) -> seqbf rows 0..Q-1 (bf16)
__global__ __launch_bounds__(256) void k_mean_reduce(const float* __restrict__ partial,
                                                     const float* __restrict__ w,
                                                     unsigned short* __restrict__ seqbf) {
  int m = blockIdx.x;  // 0..Q_-1
  float rs = 1.f / (w[m] + 0.001f);
  for (int n = threadIdx.x; n < C_; n += 256) {
    float s = 0.f;
    #pragma unroll
    for (int kc = 0; kc < KSPLIT; kc++)
      s += partial[((size_t)kc * 256 + m) * C_ + n];
    seqbf[(size_t)m * C_ + n] = f2bf(s * rs);
  }
}

// ---------------------------------------------------------------------------
// Split-K bf16 MFMA GEMM for small-M projections, 2-phase. K=1024, SK chunks.
__global__ __launch_bounds__(256) void k_gemm_splitk_bf(const unsigned short* __restrict__ A,
                                                        const unsigned short* __restrict__ B,
                                                        float* __restrict__ partial,
                                                        int M, int K) {
  __shared__ __attribute__((aligned(16))) unsigned short As[2][GBM][GBK];
  __shared__ __attribute__((aligned(16))) unsigned short Bs[2][GBN][GBK];
  int bm = blockIdx.y * GBM, bn = blockIdx.x * GBN;
  int kc = blockIdx.z;
  int kchunk = K / SK;
  int tid = threadIdx.x;
  int wid = tid >> 6, lane = tid & 63;
  int wr = wid >> 1, wc = wid & 1;
  int fq = lane >> 4, fr = lane & 15;
  int srow = lane >> 2;
  int scol = (lane & 3) * 8;

  auto stage = [&](int buf, int k0) {
    #pragma unroll
    for (int i = 0; i < 2; i++) {
      int r = wid * 32 + i * 16 + srow;
      int gA = bm + r; if (gA > M - 1) gA = M - 1;
      __builtin_amdgcn_global_load_lds(
          (const __attribute__((address_space(1))) void*)(A + (size_t)gA * K + k0 + scol),
          (__attribute__((address_space(3))) void*)((char*)&As[buf][0][0] + (wid * 2 + i) * 1024),
          16, 0, 0);
      __builtin_amdgcn_global_load_lds(
          (const __attribute__((address_space(1))) void*)(B + (size_t)(bn + r) * K + k0 + scol),
          (__attribute__((address_space(3))) void*)((char*)&Bs[buf][0][0] + (wid * 2 + i) * 1024),
          16, 0, 0);
    }
  };

  f32x4 acc[4][4] = {};
  int kbeg = kc * kchunk;
  const int NT = kchunk / GBK;
  stage(0, kbeg);
  __syncthreads();
  int cur = 0;
  for (int it = 0; it < NT; it++) {
    if (it + 1 < NT) stage(cur ^ 1, kbeg + (it + 1) * GBK);
    bf16x8 af[4], bfr[4];
    #pragma unroll
    for (int mi = 0; mi < 4; mi++)
      af[mi] = *(const bf16x8*)&As[cur][wr * 64 + mi * 16 + fr][fq * 8];
    #pragma unroll
    for (int ni = 0; ni < 4; ni++)
      bfr[ni] = *(const bf16x8*)&Bs[cur][wc * 64 + ni * 16 + fr][fq * 8];
    #pragma unroll
    for (int mi = 0; mi < 4; mi++)
      #pragma unroll
      for (int ni = 0; ni < 4; ni++)
        acc[mi][ni] = __builtin_amdgcn_mfma_f32_16x16x32_bf16(bfr[ni], af[mi], acc[mi][ni], 0, 0, 0);
    __syncthreads();
    cur ^= 1;
  }
  #pragma unroll
  for (int ni = 0; ni < 4; ni++) {
    int n0 = bn + wc * 64 + ni * 16 + fq * 4;
    #pragma unroll
    for (int mi = 0; mi < 4; mi++) {
      int m = bm + wr * 64 + mi * 16 + fr;
      *(f32x4*)&partial[((size_t)kc * 256 + m) * C_ + n0] = acc[mi][ni];
    }
  }
}

// ---------------------------------------------------------------------------
__global__ __launch_bounds__(256) void k_splitk_reduce(const float* __restrict__ partial,
                                                       const float* __restrict__ bias,
                                                       float* __restrict__ outf) {
  int m = blockIdx.x;
  for (int n = threadIdx.x; n < C_; n += 256) {
    float s = 0.f;
    #pragma unroll
    for (int kc = 0; kc < SK; kc++)
      s += partial[((size_t)kc * 256 + m) * C_ + n];
    outf[(size_t)m * C_ + n] = s + bias[n];
  }
}

// ---------------------------------------------------------------------------
// Sparse gather attention, split across ASPLIT blocks per (q,h).
__global__ __launch_bounds__(256) void k_attn_split(const float* __restrict__ qb,
                                                    const unsigned short* __restrict__ kb,
                                                    const unsigned short* __restrict__ vb,
                                                    const int* __restrict__ cnt_g,
                                                    const int* __restrict__ idxg,
                                                    float* __restrict__ pmax,
                                                    float* __restrict__ psum,
                                                    float* __restrict__ pacc) {
  int q = blockIdx.x, h = blockIdx.y, sp = blockIdx.z;
  int tid = threadIdx.x;
  int lane = tid & 63, wid = tid >> 6;

  __shared__ float qs[64];
  __shared__ float sc[CAP / ASPLIT];   // 128
  __shared__ int   ls[CAP / ASPLIT];
  __shared__ float wred[4];
  __shared__ float accb[4][64];

  int cnt = cnt_g[q];
  int cq = (cnt + ASPLIT - 1) / ASPLIT;
  int beg = sp * cq;
  int end = beg + cq; if (end > cnt) end = cnt;
  int ns = end - beg; if (ns < 0) ns = 0;

  if (tid < 64) qs[tid] = qb[(size_t)q * C_ + h * HD_ + tid] * 0.125f;
  __syncthreads();

  if (tid < ns) {
    int l = idxg[(size_t)q * CAP + beg + tid];
    ls[tid] = l;
    const u16x8* kr = (const u16x8*)(kb + (size_t)l * C_ + h * HD_);
    float s = 0.f;
    #pragma unroll
    for (int v8 = 0; v8 < 8; v8++) {
      u16x8 kv = kr[v8];
      #pragma unroll
      for (int e = 0; e < 8; e++) s = fmaf(qs[v8 * 8 + e], bf2f(kv[e]), s);
    }
    sc[tid] = s;
  }
  __syncthreads();

  float lm = (tid < ns) ? sc[tid] : -INFINITY;
  #pragma unroll
  for (int off = 32; off; off >>= 1) lm = fmaxf(lm, __shfl_xor(lm, off));
  if (lane == 0) wred[wid] = lm;
  __syncthreads();
  float m4 = fmaxf(fmaxf(wred[0], wred[1]), fmaxf(wred[2], wred[3]));

  float e = 0.f;
  if (tid < ns) {
    e = expf(sc[tid] - m4);
    sc[tid] = e;
  }
  float lsum = e;
  #pragma unroll
  for (int off = 32; off; off >>= 1) lsum += __shfl_xor(lsum, off);
  __syncthreads();
  if (lane == 0) wred[wid] = lsum;
  __syncthreads();
  float S4 = wred[0] + wred[1] + wred[2] + wred[3];

  float acc = 0.f;
  for (int j = wid; j < ns; j += 4)
    acc = fmaf(sc[j], bf2f(vb[(size_t)ls[j] * C_ + h * HD_ + lane]), acc);
  accb[wid][lane] = acc;
  __syncthreads();

  int pidx = (q * NH_ + h) * ASPLIT + sp;
  if (tid < 64)
    pacc[(size_t)pidx * 64 + tid] =
        accb[0][tid] + accb[1][tid] + accb[2][tid] + accb[3][tid];
  if (tid == 0) {
    pmax[pidx] = (ns > 0) ? m4 : -INFINITY;
    psum[pidx] = S4;
  }
}

// ---------------------------------------------------------------------------
__global__ __launch_bounds__(64) void k_attn_merge(const float* __restrict__ pmax,
                                                   const float* __restrict__ psum,
                                                   const float* __restrict__ pacc,
                                                   unsigned short* __restrict__ ctxbf) {
  int q = blockIdx.x, h = blockIdx.y;
  int d = threadIdx.x;
  int base = (q * NH_ + h) * ASPLIT;
  float M = -INFINITY;
  #pragma unroll
  for (int s = 0; s < ASPLIT; s++) M = fmaxf(M, pmax[base + s]);
  float S = 0.f, a = 0.f;
  #pragma unroll
  for (int s = 0; s < ASPLIT; s++) {
    float wgt = expf(pmax[base + s] - M);
    S += psum[base + s] * wgt;
    a += pacc[(size_t)(base + s) * 64 + d] * wgt;
  }
  ctxbf[(size_t)q * C_ + h * HD_ + d] = f2bf(a / S);
}

// ---------------------------------------------------------------------------
extern "C" void kernel_launch(void* const* d_in, const int* in_sizes, int n_in,
                              void* d_out, int out_size, void* d_ws, size_t ws_size,
                              hipStream_t stream) {
  const float* x     = (const float*)d_in[0];
  const float* masks = (const float*)d_in[1];
  const float* Wq    = (const float*)d_in[2];
  const float* bq    = (const float*)d_in[3];
  const float* Wk    = (const float*)d_in[4];
  const float* bk    = (const float*)d_in[5];
  const float* Wv    = (const float*)d_in[6];
  const float* bv    = (const float*)d_in[7];
  const float* Wc    = (const float*)d_in[8];
  const float* bc    = (const float*)d_in[9];
  float* out = (float*)d_out;

  char* p = (char*)d_ws;
  auto alloc = [&](size_t bytes) {
    char* r = p;
    p += (bytes + 255) & ~(size_t)255;
    return r;
  };
  float* msig    = (float*)alloc((size_t)Q_ * HW_ * 4);
  float* w       = (float*)alloc(1024);
  float* qbuf    = (float*)alloc((size_t)Q_ * C_ * 4);
  float* partial = (float*)alloc((size_t)KSPLIT * 256 * C_ * 4);
  int*   cnt     = (int*)alloc(1024);
  int*   idxg    = (int*)alloc((size_t)Q_ * CAP * 4);
  float* pmax    = (float*)alloc((size_t)Q_ * NH_ * ASPLIT * 4);
  float* psum    = (float*)alloc((size_t)Q_ * NH_ * ASPLIT * 4);
  float* pacc    = (float*)alloc((size_t)Q_ * NH_ * ASPLIT * 64 * 4);
  unsigned short* msigbf = (unsigned short*)alloc((size_t)256 * HW_ * 2);
  unsigned short* xbf    = (unsigned short*)alloc((size_t)C_ * HW_ * 2);
  unsigned short* seqbf  = (unsigned short*)alloc((size_t)L_ * C_ * 2);
  unsigned short* wkbf   = (unsigned short*)alloc((size_t)C_ * C_ * 2);
  unsigned short* wvbf   = (unsigned short*)alloc((size_t)C_ * C_ * 2);
  unsigned short* wqbf   = (unsigned short*)alloc((size_t)C_ * C_ * 2);
  unsigned short* wcbf   = (unsigned short*)alloc((size_t)C_ * C_ * 2);
  unsigned short* ctxbf  = (unsigned short*)alloc((size_t)256 * C_ * 2);
  unsigned short* kbuf   = (unsigned short*)alloc((size_t)L_ * C_ * 2);
  unsigned short* vbuf   = (unsigned short*)alloc((size_t)L_ * C_ * 2);

  k_sigmoid_w<<<256, 256, 0, stream>>>(masks, msig, msigbf, w);
  k_compact<<<Q_, 256, 0, stream>>>(msig, cnt, idxg);
  k_xcast<<<dim3(HW_ / 32, C_ / 32), dim3(32, 8), 0, stream>>>(x, xbf, seqbf);
  k_cast4<<<dim3(C_ * C_ / 1024, 4), 256, 0, stream>>>(Wk, Wv, Wq, Wc,
                                                       wkbf, wvbf, wqbf, wcbf);
  // mean: split-K MFMA + reduce (writes seqbf rows 0..Q-1)
  k_gemm_meank<<<dim3(C_ / GBN, 2, KSPLIT), 256, 0, stream>>>(msigbf, xbf, partial);
  k_mean_reduce<<<Q_, 256, 0, stream>>>(partial, w, seqbf);
  // Q projection (bf16 split-K)
  k_gemm_splitk_bf<<<dim3(C_ / GBN, 2, SK), 256, 0, stream>>>(seqbf, wqbf, partial, Q_, C_);
  k_splitk_reduce<<<Q_, 256, 0, stream>>>(partial, bq, qbuf);
  // Fused K+V projections (bf16 MFMA, bf16 outputs), XCD-local tile order
  k_gemm_kv<<<8 * ((L_ + GBM - 1) / GBM), 512, 0, stream>>>(
      seqbf, wkbf, wvbf, bk, bv, kbuf, vbuf, L_, C_);
  // sparse attention (split + merge -> ctxbf)
  k_attn_split<<<dim3(Q_, NH_, ASPLIT), 256, 0, stream>>>(
      qbuf, kbuf, vbuf, cnt, idxg, pmax, psum, pacc);
  k_attn_merge<<<dim3(Q_, NH_), 64, 0, stream>>>(pmax, psum, pacc, ctxbf);
  // output projection (bf16 split-K)
  k_gemm_splitk_bf<<<dim3(C_ / GBN, 2, SK), 256, 0, stream>>>(ctxbf, wcbf, partial, Q_, C_);
  k_splitk_reduce<<<Q_, 256, 0, stream>>>(partial, bc, out);
}